// Round 16
// baseline (211.848 us; speedup 1.0000x reference)
//
#include <hip/hip_runtime.h>
#include <hip/hip_bf16.h>
#include <stdint.h>

#define DEVINL __device__ __forceinline__

typedef __attribute__((ext_vector_type(4))) float f32x4;
typedef __attribute__((ext_vector_type(8))) __bf16 bfv8;
typedef __attribute__((ext_vector_type(8))) short s16x8;
typedef __attribute__((ext_vector_type(4))) short s16x4;

// ---- helpers ----
DEVINL short f2bf(float f) {  // fp32 -> bf16 bits, RTNE
  union { float f; unsigned u; } v; v.f = f;
  unsigned r = v.u + 0x7FFFu + ((v.u >> 16) & 1u);
  return (short)(r >> 16);
}
DEVINL float bf2f(short h) {
  union { unsigned u; float f; } v; v.u = ((unsigned)(unsigned short)h) << 16;
  return v.f;
}
DEVINL void gload_lds16(const void* g, void* l) {
  __builtin_amdgcn_global_load_lds((__attribute__((address_space(1))) unsigned*)(g),
                                   (__attribute__((address_space(3))) unsigned*)(l),
                                   16, 0, 0);
}
#define S_BARRIER() __builtin_amdgcn_s_barrier()
#define MEMORD() asm volatile("" ::: "memory")
template <int N> DEVINL void vmwaitc() {
  asm volatile("s_waitcnt vmcnt(%0)" :: "i"(N) : "memory");
}
// bijective XCD swizzle (n % 8 == 0)
DEVINL int xswz(int p, int n) { return (p & 7) * (n >> 3) + (p >> 3); }

// ======== r7 read-ahead core (best measured): 256x(NF*64) tile, BK=32, RING slots ========
template <int BU, int NF, int RING>
DEVINL void gemm_core(const short* __restrict__ Ag, const short* __restrict__ Bg,
                      int lda, int ldb, int m0, int n0, int nkt,
                      short* lds, f32x4 (&acc)[8][NF]) {
  constexpr int U = 2 + BU;
  constexpr int SLOT = 8192 + BU * 4096;
  const int tid = threadIdx.x;
  const int w = tid >> 6, l = tid & 63;
  const int wm = w >> 2, wn = w & 3;
  const int lr = l & 15, lg = l >> 4;
  const int stg_row = w * 16 + (l >> 2);
  const int stg_col = (((l & 3) ^ ((l >> 3) & 3)) << 3);
  const int ck = ((lg ^ ((lr >> 1) & 3)) << 3);
  const int aro = (wm * 128 + lr) * 32 + ck;
  const int bro = 8192 + (wn * (NF * 16) + lr) * 32 + ck;
  const int dW = w * 512;
#define STAGE_A(t) { short* S_ = lds + ((t) % RING) * SLOT;                                \
    gload_lds16(Ag + (size_t)(m0 + stg_row) * lda + (t) * 32 + stg_col, S_ + dW);          \
    gload_lds16(Ag + (size_t)(m0 + 128 + stg_row) * lda + (t) * 32 + stg_col,              \
                S_ + 4096 + dW); }
#define STAGE_B(t) { short* S_ = lds + ((t) % RING) * SLOT;                                \
    _Pragma("unroll")                                                                      \
    for (int u_ = 0; u_ < BU; ++u_)                                                        \
      gload_lds16(Bg + (size_t)(n0 + u_ * 128 + stg_row) * ldb + (t) * 32 + stg_col,       \
                  S_ + 8192 + u_ * 4096 + dW); }
#pragma unroll
  for (int t = 0; t < RING - 1; ++t) { STAGE_A(t); STAGE_B(t); }
  vmwaitc<(RING - 2) * U>(); S_BARRIER(); MEMORD();
  bfv8 aA[4], aB[4], bA[NF], bB[NF];
  {
    const short* Sp = lds;
#pragma unroll
    for (int mf = 0; mf < 4; ++mf) aA[mf] = *(const bfv8*)(Sp + aro + mf * 512);
#pragma unroll
    for (int nf = 0; nf < NF; ++nf) bA[nf] = *(const bfv8*)(Sp + bro + nf * 512);
  }
#pragma unroll 1
  for (int kt = 0; kt < nkt; kt += 2) {
    const short* S1 = lds + ((kt + 1) % RING) * SLOT;
    const short* S2 = lds + ((kt + 2) % RING) * SLOT;
    const short* S0 = lds + (kt % RING) * SLOT;
    if (kt + 2 < nkt) STAGE_A(kt + 2);
#pragma unroll
    for (int mf = 0; mf < 4; ++mf) aB[mf] = *(const bfv8*)(S0 + aro + 2048 + mf * 512);
#pragma unroll
    for (int mf = 0; mf < 4; ++mf)
#pragma unroll
      for (int nf = 0; nf < NF; ++nf)
        acc[mf][nf] = __builtin_amdgcn_mfma_f32_16x16x32_bf16(aA[mf], bA[nf], acc[mf][nf], 0, 0, 0);
    if (kt + 2 < nkt) vmwaitc<2>(); else vmwaitc<0>();
    S_BARRIER(); MEMORD();
    if (kt + 2 < nkt) STAGE_B(kt + 2);
#pragma unroll
    for (int mf = 0; mf < 4; ++mf) aA[mf] = *(const bfv8*)(S1 + aro + mf * 512);
#pragma unroll
    for (int nf = 0; nf < NF; ++nf) bB[nf] = *(const bfv8*)(S1 + bro + nf * 512);
#pragma unroll
    for (int mf = 0; mf < 4; ++mf)
#pragma unroll
      for (int nf = 0; nf < NF; ++nf)
        acc[4 + mf][nf] = __builtin_amdgcn_mfma_f32_16x16x32_bf16(aB[mf], bA[nf], acc[4 + mf][nf], 0, 0, 0);
    S_BARRIER(); MEMORD();
    if (kt + 3 < nkt) STAGE_A(kt + 3);
#pragma unroll
    for (int mf = 0; mf < 4; ++mf) aB[mf] = *(const bfv8*)(S1 + aro + 2048 + mf * 512);
#pragma unroll
    for (int mf = 0; mf < 4; ++mf)
#pragma unroll
      for (int nf = 0; nf < NF; ++nf)
        acc[mf][nf] = __builtin_amdgcn_mfma_f32_16x16x32_bf16(aA[mf], bB[nf], acc[mf][nf], 0, 0, 0);
    if (kt + 3 < nkt) vmwaitc<2>(); else vmwaitc<0>();
    S_BARRIER(); MEMORD();
    if (kt + 3 < nkt) STAGE_B(kt + 3);
    if (kt + 2 < nkt) {
#pragma unroll
      for (int mf = 0; mf < 4; ++mf) aA[mf] = *(const bfv8*)(S2 + aro + mf * 512);
#pragma unroll
      for (int nf = 0; nf < NF; ++nf) bA[nf] = *(const bfv8*)(S2 + bro + nf * 512);
    }
#pragma unroll
    for (int mf = 0; mf < 4; ++mf)
#pragma unroll
      for (int nf = 0; nf < NF; ++nf)
        acc[4 + mf][nf] = __builtin_amdgcn_mfma_f32_16x16x32_bf16(aB[mf], bB[nf], acc[4 + mf][nf], 0, 0, 0);
    S_BARRIER(); MEMORD();
  }
#undef STAGE_A
#undef STAGE_B
}

// ============ prep: cast X,Y,Wq,Wk -> bf16 + Wv transpose-cast ============
__global__ __launch_bounds__(256) void prep_kernel(
    const float* __restrict__ q, const float* __restrict__ v,
    const float* __restrict__ Wq, const float* __restrict__ Wk, const float* __restrict__ Wv,
    short* __restrict__ Qc, short* __restrict__ Vc,
    short* __restrict__ Wqc, short* __restrict__ Wkc, short* __restrict__ WTv) {
  __shared__ float tile[64][65];
  const int bx = blockIdx.x;
  if (bx < 9216) {
    const float* src; short* dst; int off;
    if (bx < 4096)      { src = q;  dst = Qc;  off = bx; }
    else if (bx < 8192) { src = v;  dst = Vc;  off = bx - 4096; }
    else if (bx < 8704) { src = Wq; dst = Wqc; off = bx - 8192; }
    else                { src = Wk; dst = Wkc; off = bx - 8704; }
    const size_t i = ((size_t)off * 256 + threadIdx.x) * 8;
    f32x4 x0 = *(const f32x4*)(src + i);
    f32x4 x1 = *(const f32x4*)(src + i + 4);
    s16x8 o;
#pragma unroll
    for (int j = 0; j < 4; ++j) { o[j] = f2bf(x0[j]); o[4 + j] = f2bf(x1[j]); }
    *(s16x8*)(dst + i) = o;
  } else {
    const int xx = bx - 9216;  // [0,256): Wv -> WTv[n][k]
    const int k0 = (xx & 15) << 6, n0 = (xx >> 4) << 6;
    const int c = threadIdx.x & 63, r0 = threadIdx.x >> 6;
#pragma unroll
    for (int i = 0; i < 16; ++i) {
      int r = (i << 2) + r0;
      tile[r][c] = Wv[(size_t)(k0 + r) * 1024 + n0 + c];
    }
    __syncthreads();
#pragma unroll
    for (int i = 0; i < 16; ++i) {
      int a = (i << 2) + r0;
      WTv[(size_t)(n0 + a) * 1024 + k0 + c] = f2bf(tile[c][a]);
    }
  }
}

// ============ bias correction: flag = any(bq != 0); v1 = Wk . bq ============
__global__ __launch_bounds__(256) void bias0_kernel(const float* __restrict__ Wk,
                                                    const float* __restrict__ bq,
                                                    float* __restrict__ v1,
                                                    float* __restrict__ flagp) {
  __shared__ float red[256];
  const int t = threadIdx.x;
  float any = 0.f;
  for (int i = t; i < 1024; i += 256) any += fabsf(bq[i]);
  red[t] = any; __syncthreads();
  for (int s = 128; s > 0; s >>= 1) { if (t < s) red[t] += red[t + s]; __syncthreads(); }
  const float fl = red[0];
  if (t == 0) *flagp = fl;
  if (fl != 0.f) {
    for (int r = t; r < 1024; r += 256) {
      float acc = 0.f;
      for (int u = 0; u < 1024; ++u) acc += Wk[(size_t)r * 1024 + u] * bq[u];
      v1[r] = acc;
    }
  }
}

// ============ tvec[t] = Y[t] . v1 (0 if flag==0) ============
__global__ __launch_bounds__(256) void tvec_kernel(const float* __restrict__ Y,
                                                   const float* __restrict__ v1,
                                                   const float* __restrict__ flagp,
                                                   float* __restrict__ tvec) {
  const int t = blockIdx.x * 256 + threadIdx.x;  // [0, 8192)
  if (*flagp == 0.f) { tvec[t] = 0.f; return; }
  float acc = 0.f;
  for (int d = 0; d < 1024; ++d) acc += Y[(size_t)t * 1024 + d] * v1[d];
  tvec[t] = acc;
}

// ==== mker split-K: Part[ks][e][d] = sum_{u in ks-quarter} Wk[e,u] Wq[d,u] ====
__global__ __launch_bounds__(512, 2) void mker_kernel(const short* __restrict__ Wkc,
                                                      const short* __restrict__ Wqc,
                                                      float* __restrict__ Part) {
  __shared__ short lds[36864];
  const int o = xswz(blockIdx.x, 128);
  const int ks = o >> 5, r = o & 31;
  const int bm = r >> 3, bn = r & 7;
  const int m0 = bm * 256, n0 = bn * 128;
  f32x4 acc[8][2];
#pragma unroll
  for (int i = 0; i < 8; ++i)
#pragma unroll
    for (int j = 0; j < 2; ++j) acc[i][j] = (f32x4){0.f, 0.f, 0.f, 0.f};
  gemm_core<1, 2, 3>(Wkc + ks * 256, Wqc + ks * 256, 1024, 1024, m0, n0, 8, lds, acc);
  float* O = Part + (size_t)ks * 1048576;
  const int l = threadIdx.x & 63, w = threadIdx.x >> 6;
  const int wm = w >> 2, wn = w & 3, lr = l & 15, lg = l >> 4;
#pragma unroll
  for (int i = 0; i < 8; ++i) {
    const int row0 = m0 + wm * 128 + (i >> 2) * 64 + (i & 3) * 16 + lg * 4;
#pragma unroll
    for (int nf = 0; nf < 2; ++nf) {
      const int col = n0 + wn * 32 + nf * 16 + lr;
#pragma unroll
      for (int j = 0; j < 4; ++j)
        O[(size_t)(row0 + j) * 1024 + col] = acc[i][nf][j];
    }
  }
}

// ==== mkred: MT[i] = bf16(sum_ks Part[ks][i]) ====
__global__ __launch_bounds__(256) void mkred_kernel(const float* __restrict__ Part,
                                                    short* __restrict__ MT) {
  const size_t i = ((size_t)blockIdx.x * 256 + threadIdx.x) * 4;
  f32x4 a = *(const f32x4*)(Part + i);
  f32x4 b = *(const f32x4*)(Part + 1048576 + i);
  f32x4 c = *(const f32x4*)(Part + 2097152 + i);
  f32x4 d = *(const f32x4*)(Part + 3145728 + i);
  s16x4 o;
#pragma unroll
  for (int j = 0; j < 4; ++j) o[j] = f2bf(a[j] + b[j] + c[j] + d[j]);
  *(s16x4*)(MT + i) = o;
}

// ==== FUSED qproj + vproj: grid 512 (o<256 -> qproj, else vproj), 2 blk/CU ====
// qproj: A'[s][e] = sum_d X[s,d] MT[e,d]   (tile 256x128, 32 bm x 8 bn)
// vproj: VT[b][u][t] = (Y.Wv + bv)^T        (tile 256x128, 32 bm x 8 bn, LDS transpose)
__global__ __launch_bounds__(512, 4) void qvproj_kernel(
    const short* __restrict__ Qc, const short* __restrict__ MT, short* __restrict__ Ap,
    const short* __restrict__ Vc, const short* __restrict__ WTv,
    const float* __restrict__ bv, short* __restrict__ VT) {
  __shared__ short lds[36864];
  const int o = xswz(blockIdx.x, 512);
  const int sel = o >> 8, r = o & 255;
  const int bm = r >> 3, bn = r & 7;          // bm:[0,32) bn:[0,8)
  const int m0 = bm * 256, n0 = bn * 128;
  f32x4 acc[8][2];
#pragma unroll
  for (int i = 0; i < 8; ++i)
#pragma unroll
    for (int j = 0; j < 2; ++j) acc[i][j] = (f32x4){0.f, 0.f, 0.f, 0.f};
  const int tid = threadIdx.x;
  const int w = tid >> 6, l = tid & 63;
  const int wm = w >> 2, wn = w & 3, lr = l & 15, lg = l >> 4;
  if (sel == 0) {
    gemm_core<1, 2, 3>(Qc, MT, 1024, 1024, m0, n0, 32, lds, acc);
#pragma unroll
    for (int i = 0; i < 8; ++i) {
      const int row0 = m0 + wm * 128 + (i >> 2) * 64 + (i & 3) * 16 + lg * 4;  // <= 8191
#pragma unroll
      for (int nf = 0; nf < 2; ++nf) {
        const int col = n0 + wn * 32 + nf * 16 + lr;  // <= 1023
#pragma unroll
        for (int j = 0; j < 4; ++j)
          Ap[(size_t)(row0 + j) * 1024 + col] = f2bf(acc[i][nf][j]);
      }
    }
  } else {
    gemm_core<1, 2, 3>(Vc, WTv, 1024, 1024, m0, n0, 32, lds, acc);
    __syncthreads();
    short* lt = lds;  // [u_local 0..127][t_local 0..255], stride 264
#pragma unroll
    for (int i = 0; i < 8; ++i) {
      const int tl = wm * 128 + (i >> 2) * 64 + (i & 3) * 16 + lg * 4;
#pragma unroll
      for (int nf = 0; nf < 2; ++nf) {
        const int ul = wn * 32 + nf * 16 + lr;
        const float bb = bv[n0 + ul];
        s16x4 pk;
#pragma unroll
        for (int j = 0; j < 4; ++j) pk[j] = f2bf(acc[i][nf][j] + bb);
        *(s16x4*)&lt[ul * 264 + tl] = pk;
      }
    }
    __syncthreads();
    const int b = m0 >> 11, t0 = m0 & 2047;
#pragma unroll
    for (int it = 0; it < 8; ++it) {
      const int cid = it * 512 + tid;
      const int u = cid >> 5, tc = cid & 31;
      s16x8 v8 = *(const s16x8*)&lt[u * 264 + tc * 8];
      *(s16x8*)(VT + ((size_t)b * 1024 + n0 + u) * 2048 + t0 + tc * 8) = v8;
    }
  }
}

// ==== QK^T: scores=(A'.Vc^T + tvec)/32; tile 256x128, grid 512 ====
__global__ __launch_bounds__(512, 4) void qkt_kernel(const short* __restrict__ Ap,
                                                     const short* __restrict__ Vc,
                                                     const float* __restrict__ tvec,
                                                     short* __restrict__ sb0,
                                                     short* __restrict__ sb3) {
  __shared__ short lds[36864];
  const int o = xswz(blockIdx.x, 512);
  const int bt = o >> 7, r = o & 127;
  const int bm = r >> 4, bn = r & 15;
  const short* A = Ap + (size_t)bt * 2097152;
  const short* B = Vc + (size_t)bt * 2097152;
  short* O = (bt < 3) ? (sb0 + (size_t)bt * 4194304) : sb3;
  const int m0 = bm * 256, n0 = bn * 128;
  f32x4 acc[8][2];
#pragma unroll
  for (int i = 0; i < 8; ++i)
#pragma unroll
    for (int j = 0; j < 2; ++j) acc[i][j] = (f32x4){0.f, 0.f, 0.f, 0.f};
  gemm_core<1, 2, 3>(A, B, 1024, 1024, m0, n0, 32, lds, acc);
  const int tid = threadIdx.x;
  const int w = tid >> 6, l = tid & 63;
  const int wm = w >> 2, wn = w & 3, lr = l & 15, lg = l >> 4;
  float tv[2];
#pragma unroll
  for (int nf = 0; nf < 2; ++nf) tv[nf] = tvec[bt * 2048 + n0 + wn * 32 + nf * 16 + lr];
#pragma unroll
  for (int i = 0; i < 8; ++i) {
    const int row0 = m0 + wm * 128 + (i >> 2) * 64 + (i & 3) * 16 + lg * 4;
#pragma unroll
    for (int nf = 0; nf < 2; ++nf) {
      const int col = n0 + wn * 32 + nf * 16 + lr;
#pragma unroll
      for (int j = 0; j < 4; ++j)
        O[(size_t)(row0 + j) * 2048 + col] = f2bf((acc[i][nf][j] + tv[nf]) * 0.03125f);
    }
  }
}

// ==== PV split-K=2: grid 512 (2 kh x 4 bt x 8 bm x 8 bn), nkt=32, 2 blk/CU ====
// kh=0 -> Out, kh=1 -> Part (fp32); add folds. (split-K numerics validated r9.)
__global__ __launch_bounds__(512, 4) void pv_kernel(const short* __restrict__ sb0,
                                                    const short* __restrict__ sb3,
                                                    const short* __restrict__ VT,
                                                    float* __restrict__ Out,
                                                    float* __restrict__ Part) {
  __shared__ short lds[36864];
  const int o = xswz(blockIdx.x, 512);
  const int kh = o >> 8;                       // [0,2)
  const int bt = (o >> 6) & 3;                 // [0,4)
  const int bm = (o >> 3) & 7, bn = o & 7;     // bm:[0,8) bn:[0,8)
  const short* A = ((bt < 3) ? (sb0 + (size_t)bt * 4194304) : sb3) + kh * 1024;
  const short* B = VT + (size_t)bt * 2097152 + kh * 1024;
  float* O = (kh ? Part : Out) + (size_t)bt * 2097152;
  const int m0 = bm * 256, n0 = bn * 128;
  f32x4 acc[8][2];
#pragma unroll
  for (int i = 0; i < 8; ++i)
#pragma unroll
    for (int j = 0; j < 2; ++j) acc[i][j] = (f32x4){0.f, 0.f, 0.f, 0.f};
  gemm_core<1, 2, 3>(A, B, 2048, 2048, m0, n0, 32, lds, acc);
  const int l = threadIdx.x & 63, w = threadIdx.x >> 6;
  const int wm = w >> 2, wn = w & 3, lr = l & 15, lg = l >> 4;
#pragma unroll
  for (int i = 0; i < 8; ++i) {
    const int row0 = m0 + wm * 128 + (i >> 2) * 64 + (i & 3) * 16 + lg * 4;  // <= 2047
#pragma unroll
    for (int nf = 0; nf < 2; ++nf) {
      const int col = n0 + wn * 32 + nf * 16 + lr;  // <= 1023
#pragma unroll
      for (int j = 0; j < 4; ++j)
        O[(size_t)(row0 + j) * 1024 + col] = acc[i][nf][j];
    }
  }
}

// ============ add: d_out += Part (8M floats) ============
__global__ __launch_bounds__(256) void add_kernel(float* __restrict__ Out,
                                                  const float* __restrict__ Part) {
  const size_t i = ((size_t)blockIdx.x * 256 + threadIdx.x) * 4;
  f32x4 a = *(const f32x4*)(Out + i);
  f32x4 b = *(const f32x4*)(Part + i);
#pragma unroll
  for (int j = 0; j < 4; ++j) a[j] += b[j];
  *(f32x4*)(Out + i) = a;
}

// ============ Row softmax, in-place on bf16 scores ============
__global__ __launch_bounds__(256) void softmax_kernel(short* __restrict__ sb0,
                                                      short* __restrict__ sb3) {
  const int row = blockIdx.x;
  const int bt = row >> 11;
  short* p = ((bt < 3) ? (sb0 + (size_t)bt * 4194304) : sb3) + (size_t)(row & 2047) * 2048;
  const int tid = threadIdx.x;
  const int w = tid >> 6, l = tid & 63;
  s16x8 v = *(const s16x8*)(p + tid * 8);
  float f[8];
#pragma unroll
  for (int j = 0; j < 8; ++j) f[j] = bf2f(v[j]);
  float m = f[0];
#pragma unroll
  for (int j = 1; j < 8; ++j) m = fmaxf(m, f[j]);
#pragma unroll
  for (int o = 32; o > 0; o >>= 1) m = fmaxf(m, __shfl_xor(m, o, 64));
  __shared__ float redm[4], reds[4];
  if (l == 0) redm[w] = m;
  __syncthreads();
  m = fmaxf(fmaxf(redm[0], redm[1]), fmaxf(redm[2], redm[3]));
  float s = 0.f;
#pragma unroll
  for (int j = 0; j < 8; ++j) { f[j] = __expf(f[j] - m); s += f[j]; }
#pragma unroll
  for (int o = 32; o > 0; o >>= 1) s += __shfl_xor(s, o, 64);
  if (l == 0) reds[w] = s;
  __syncthreads();
  s = reds[0] + reds[1] + reds[2] + reds[3];
  const float inv = 1.f / s;
  s16x8 o8;
#pragma unroll
  for (int j = 0; j < 8; ++j) o8[j] = f2bf(f[j] * inv);
  *(s16x8*)(p + tid * 8) = o8;
}

// ============ launch ============
extern "C" void kernel_launch(void* const* d_in, const int* in_sizes, int n_in,
                              void* d_out, int out_size, void* d_ws, size_t ws_size,
                              hipStream_t stream) {
  const float* query = (const float*)d_in[0];
  const float* value = (const float*)d_in[1];
  const float* Wq = (const float*)d_in[2];
  const float* bq = (const float*)d_in[3];
  const float* Wk = (const float*)d_in[4];
  // bk: per-row-constant score contribution -> cancels in softmax
  const float* Wv = (const float*)d_in[6];
  const float* bv = (const float*)d_in[7];

  // Workspace (~80.2 MB of 86):
  //  0-2 Wqc | 2-4 Wkc | 4-6 MT | 6-8 WTv  [dead before qkt]
  //  8-24 Qc [prep->qvproj]  24-40 Vc [prep->qkt]
  //  40-56 MPart fp32 [mker->mkred] THEN Ap [qvproj->qkt]
  //  56-72 VT [qvproj->pv]
  //  Sb: bt 0-2 @ 0-24 (dead-region reuse), bt 3 @ 72-80
  //  PvPart fp32 32MB @ 24-56 (Vc+Ap dead after qkt) [pv->add]
  //  80M: tvec(32KB) | +64K v1 | +128K flag
  char* ws = (char*)d_ws;
  short* Wqc = (short*)(ws);
  short* Wkc = (short*)(ws + ((size_t)2 << 20));
  short* MT  = (short*)(ws + ((size_t)4 << 20));
  short* WTv = (short*)(ws + ((size_t)6 << 20));
  short* Qc  = (short*)(ws + ((size_t)8 << 20));
  short* Vc  = (short*)(ws + ((size_t)24 << 20));
  float* MPart = (float*)(ws + ((size_t)40 << 20));
  short* Ap  = (short*)(ws + ((size_t)40 << 20));
  short* VT  = (short*)(ws + ((size_t)56 << 20));
  short* sb0 = (short*)(ws);
  short* sb3 = (short*)(ws + ((size_t)72 << 20));
  float* PvPart = (float*)(ws + ((size_t)24 << 20));
  float* tvec = (float*)(ws + ((size_t)80 << 20));
  float* v1   = (float*)(ws + ((size_t)80 << 20) + 65536);
  float* flagp = (float*)(ws + ((size_t)80 << 20) + 131072);

  prep_kernel<<<dim3(9472), 256, 0, stream>>>(query, value, Wq, Wk, Wv,
                                              Qc, Vc, Wqc, Wkc, WTv);
  bias0_kernel<<<dim3(1), 256, 0, stream>>>(Wk, bq, v1, flagp);
  tvec_kernel<<<dim3(32), 256, 0, stream>>>(value, v1, flagp, tvec);

  // MT = Wk.Wq^T via split-K=4 + reduce
  mker_kernel<<<dim3(128), 512, 0, stream>>>(Wkc, Wqc, MPart);
  mkred_kernel<<<dim3(1024), 256, 0, stream>>>(MPart, MT);

  // fused: A' = X.MT^T  ||  VT = (Y.Wv + bv)^T   (512 blocks, 2 blk/CU)
  qvproj_kernel<<<dim3(512), 512, 0, stream>>>(Qc, MT, Ap, Vc, WTv, bv, VT);

  // scores = (A'.Vc^T + tvec)/32
  qkt_kernel<<<dim3(512), 512, 0, stream>>>(Ap, Vc, tvec, sb0, sb3);
  softmax_kernel<<<dim3(8192), 256, 0, stream>>>(sb0, sb3);

  // out = P @ V, split-K=2 (Vc/Ap dead -> PvPart reuses 24-56M)
  pv_kernel<<<dim3(512), 512, 0, stream>>>(sb0, sb3, VT, (float*)d_out, PvPart);
  add_kernel<<<dim3(8192), 256, 0, stream>>>((float*)d_out, PvPart);
}

// Round 17
// 206.815 us; speedup vs baseline: 1.0243x; 1.0243x over previous
//
#include <hip/hip_runtime.h>
#include <hip/hip_bf16.h>
#include <stdint.h>

#define DEVINL __device__ __forceinline__

typedef __attribute__((ext_vector_type(4))) float f32x4;
typedef __attribute__((ext_vector_type(8))) __bf16 bfv8;
typedef __attribute__((ext_vector_type(8))) short s16x8;
typedef __attribute__((ext_vector_type(4))) short s16x4;

// ---- helpers ----
DEVINL short f2bf(float f) {  // fp32 -> bf16 bits, RTNE
  union { float f; unsigned u; } v; v.f = f;
  unsigned r = v.u + 0x7FFFu + ((v.u >> 16) & 1u);
  return (short)(r >> 16);
}
DEVINL float bf2f(short h) {
  union { unsigned u; float f; } v; v.u = ((unsigned)(unsigned short)h) << 16;
  return v.f;
}
DEVINL void gload_lds16(const void* g, void* l) {
  __builtin_amdgcn_global_load_lds((__attribute__((address_space(1))) unsigned*)(g),
                                   (__attribute__((address_space(3))) unsigned*)(l),
                                   16, 0, 0);
}
#define S_BARRIER() __builtin_amdgcn_s_barrier()
#define MEMORD() asm volatile("" ::: "memory")
template <int N> DEVINL void vmwaitc() {
  asm volatile("s_waitcnt vmcnt(%0)" :: "i"(N) : "memory");
}
// bijective XCD swizzle (n % 8 == 0)
DEVINL int xswz(int p, int n) { return (p & 7) * (n >> 3) + (p >> 3); }

// ======== r7 read-ahead core (best measured): 256x(NF*64) tile, BK=32, RING slots ========
template <int BU, int NF, int RING>
DEVINL void gemm_core(const short* __restrict__ Ag, const short* __restrict__ Bg,
                      int lda, int ldb, int m0, int n0, int nkt,
                      short* lds, f32x4 (&acc)[8][NF]) {
  constexpr int U = 2 + BU;
  constexpr int SLOT = 8192 + BU * 4096;
  const int tid = threadIdx.x;
  const int w = tid >> 6, l = tid & 63;
  const int wm = w >> 2, wn = w & 3;
  const int lr = l & 15, lg = l >> 4;
  const int stg_row = w * 16 + (l >> 2);
  const int stg_col = (((l & 3) ^ ((l >> 3) & 3)) << 3);
  const int ck = ((lg ^ ((lr >> 1) & 3)) << 3);
  const int aro = (wm * 128 + lr) * 32 + ck;
  const int bro = 8192 + (wn * (NF * 16) + lr) * 32 + ck;
  const int dW = w * 512;
#define STAGE_A(t) { short* S_ = lds + ((t) % RING) * SLOT;                                \
    gload_lds16(Ag + (size_t)(m0 + stg_row) * lda + (t) * 32 + stg_col, S_ + dW);          \
    gload_lds16(Ag + (size_t)(m0 + 128 + stg_row) * lda + (t) * 32 + stg_col,              \
                S_ + 4096 + dW); }
#define STAGE_B(t) { short* S_ = lds + ((t) % RING) * SLOT;                                \
    _Pragma("unroll")                                                                      \
    for (int u_ = 0; u_ < BU; ++u_)                                                        \
      gload_lds16(Bg + (size_t)(n0 + u_ * 128 + stg_row) * ldb + (t) * 32 + stg_col,       \
                  S_ + 8192 + u_ * 4096 + dW); }
#pragma unroll
  for (int t = 0; t < RING - 1; ++t) { STAGE_A(t); STAGE_B(t); }
  vmwaitc<(RING - 2) * U>(); S_BARRIER(); MEMORD();
  bfv8 aA[4], aB[4], bA[NF], bB[NF];
  {
    const short* Sp = lds;
#pragma unroll
    for (int mf = 0; mf < 4; ++mf) aA[mf] = *(const bfv8*)(Sp + aro + mf * 512);
#pragma unroll
    for (int nf = 0; nf < NF; ++nf) bA[nf] = *(const bfv8*)(Sp + bro + nf * 512);
  }
#pragma unroll 1
  for (int kt = 0; kt < nkt; kt += 2) {
    const short* S1 = lds + ((kt + 1) % RING) * SLOT;
    const short* S2 = lds + ((kt + 2) % RING) * SLOT;
    const short* S0 = lds + (kt % RING) * SLOT;
    if (kt + 2 < nkt) STAGE_A(kt + 2);
#pragma unroll
    for (int mf = 0; mf < 4; ++mf) aB[mf] = *(const bfv8*)(S0 + aro + 2048 + mf * 512);
#pragma unroll
    for (int mf = 0; mf < 4; ++mf)
#pragma unroll
      for (int nf = 0; nf < NF; ++nf)
        acc[mf][nf] = __builtin_amdgcn_mfma_f32_16x16x32_bf16(aA[mf], bA[nf], acc[mf][nf], 0, 0, 0);
    if (kt + 2 < nkt) vmwaitc<2>(); else vmwaitc<0>();
    S_BARRIER(); MEMORD();
    if (kt + 2 < nkt) STAGE_B(kt + 2);
#pragma unroll
    for (int mf = 0; mf < 4; ++mf) aA[mf] = *(const bfv8*)(S1 + aro + mf * 512);
#pragma unroll
    for (int nf = 0; nf < NF; ++nf) bB[nf] = *(const bfv8*)(S1 + bro + nf * 512);
#pragma unroll
    for (int mf = 0; mf < 4; ++mf)
#pragma unroll
      for (int nf = 0; nf < NF; ++nf)
        acc[4 + mf][nf] = __builtin_amdgcn_mfma_f32_16x16x32_bf16(aB[mf], bA[nf], acc[4 + mf][nf], 0, 0, 0);
    S_BARRIER(); MEMORD();
    if (kt + 3 < nkt) STAGE_A(kt + 3);
#pragma unroll
    for (int mf = 0; mf < 4; ++mf) aB[mf] = *(const bfv8*)(S1 + aro + 2048 + mf * 512);
#pragma unroll
    for (int mf = 0; mf < 4; ++mf)
#pragma unroll
      for (int nf = 0; nf < NF; ++nf)
        acc[mf][nf] = __builtin_amdgcn_mfma_f32_16x16x32_bf16(aA[mf], bB[nf], acc[mf][nf], 0, 0, 0);
    if (kt + 3 < nkt) vmwaitc<2>(); else vmwaitc<0>();
    S_BARRIER(); MEMORD();
    if (kt + 3 < nkt) STAGE_B(kt + 3);
    if (kt + 2 < nkt) {
#pragma unroll
      for (int mf = 0; mf < 4; ++mf) aA[mf] = *(const bfv8*)(S2 + aro + mf * 512);
#pragma unroll
      for (int nf = 0; nf < NF; ++nf) bA[nf] = *(const bfv8*)(S2 + bro + nf * 512);
    }
#pragma unroll
    for (int mf = 0; mf < 4; ++mf)
#pragma unroll
      for (int nf = 0; nf < NF; ++nf)
        acc[4 + mf][nf] = __builtin_amdgcn_mfma_f32_16x16x32_bf16(aB[mf], bB[nf], acc[4 + mf][nf], 0, 0, 0);
    S_BARRIER(); MEMORD();
  }
#undef STAGE_A
#undef STAGE_B
}

// ============ prep: cast X,Y,Wq,Wk -> bf16 + Wv transpose-cast ============
__global__ __launch_bounds__(256) void prep_kernel(
    const float* __restrict__ q, const float* __restrict__ v,
    const float* __restrict__ Wq, const float* __restrict__ Wk, const float* __restrict__ Wv,
    short* __restrict__ Qc, short* __restrict__ Vc,
    short* __restrict__ Wqc, short* __restrict__ Wkc, short* __restrict__ WTv) {
  __shared__ float tile[64][65];
  const int bx = blockIdx.x;
  if (bx < 9216) {
    const float* src; short* dst; int off;
    if (bx < 4096)      { src = q;  dst = Qc;  off = bx; }
    else if (bx < 8192) { src = v;  dst = Vc;  off = bx - 4096; }
    else if (bx < 8704) { src = Wq; dst = Wqc; off = bx - 8192; }
    else                { src = Wk; dst = Wkc; off = bx - 8704; }
    const size_t i = ((size_t)off * 256 + threadIdx.x) * 8;
    f32x4 x0 = *(const f32x4*)(src + i);
    f32x4 x1 = *(const f32x4*)(src + i + 4);
    s16x8 o;
#pragma unroll
    for (int j = 0; j < 4; ++j) { o[j] = f2bf(x0[j]); o[4 + j] = f2bf(x1[j]); }
    *(s16x8*)(dst + i) = o;
  } else {
    const int xx = bx - 9216;  // [0,256): Wv -> WTv[n][k]
    const int k0 = (xx & 15) << 6, n0 = (xx >> 4) << 6;
    const int c = threadIdx.x & 63, r0 = threadIdx.x >> 6;
#pragma unroll
    for (int i = 0; i < 16; ++i) {
      int r = (i << 2) + r0;
      tile[r][c] = Wv[(size_t)(k0 + r) * 1024 + n0 + c];
    }
    __syncthreads();
#pragma unroll
    for (int i = 0; i < 16; ++i) {
      int a = (i << 2) + r0;
      WTv[(size_t)(n0 + a) * 1024 + k0 + c] = f2bf(tile[c][a]);
    }
  }
}

// ============ bias correction: flag = any(bq != 0); v1 = Wk . bq ============
__global__ __launch_bounds__(256) void bias0_kernel(const float* __restrict__ Wk,
                                                    const float* __restrict__ bq,
                                                    float* __restrict__ v1,
                                                    float* __restrict__ flagp) {
  __shared__ float red[256];
  const int t = threadIdx.x;
  float any = 0.f;
  for (int i = t; i < 1024; i += 256) any += fabsf(bq[i]);
  red[t] = any; __syncthreads();
  for (int s = 128; s > 0; s >>= 1) { if (t < s) red[t] += red[t + s]; __syncthreads(); }
  const float fl = red[0];
  if (t == 0) *flagp = fl;
  if (fl != 0.f) {
    for (int r = t; r < 1024; r += 256) {
      float acc = 0.f;
      for (int u = 0; u < 1024; ++u) acc += Wk[(size_t)r * 1024 + u] * bq[u];
      v1[r] = acc;
    }
  }
}

// ============ tvec[t] = Y[t] . v1 (0 if flag==0) ============
__global__ __launch_bounds__(256) void tvec_kernel(const float* __restrict__ Y,
                                                   const float* __restrict__ v1,
                                                   const float* __restrict__ flagp,
                                                   float* __restrict__ tvec) {
  const int t = blockIdx.x * 256 + threadIdx.x;  // [0, 8192)
  if (*flagp == 0.f) { tvec[t] = 0.f; return; }
  float acc = 0.f;
  for (int d = 0; d < 1024; ++d) acc += Y[(size_t)t * 1024 + d] * v1[d];
  tvec[t] = acc;
}

// ==== mker split-K: Part[ks][e][d] = sum_{u in ks-quarter} Wk[e,u] Wq[d,u] ====
__global__ __launch_bounds__(512, 2) void mker_kernel(const short* __restrict__ Wkc,
                                                      const short* __restrict__ Wqc,
                                                      float* __restrict__ Part) {
  __shared__ short lds[36864];
  const int o = xswz(blockIdx.x, 128);
  const int ks = o >> 5, r = o & 31;
  const int bm = r >> 3, bn = r & 7;
  const int m0 = bm * 256, n0 = bn * 128;
  f32x4 acc[8][2];
#pragma unroll
  for (int i = 0; i < 8; ++i)
#pragma unroll
    for (int j = 0; j < 2; ++j) acc[i][j] = (f32x4){0.f, 0.f, 0.f, 0.f};
  gemm_core<1, 2, 3>(Wkc + ks * 256, Wqc + ks * 256, 1024, 1024, m0, n0, 8, lds, acc);
  float* O = Part + (size_t)ks * 1048576;
  const int l = threadIdx.x & 63, w = threadIdx.x >> 6;
  const int wm = w >> 2, wn = w & 3, lr = l & 15, lg = l >> 4;
#pragma unroll
  for (int i = 0; i < 8; ++i) {
    const int row0 = m0 + wm * 128 + (i >> 2) * 64 + (i & 3) * 16 + lg * 4;
#pragma unroll
    for (int nf = 0; nf < 2; ++nf) {
      const int col = n0 + wn * 32 + nf * 16 + lr;
#pragma unroll
      for (int j = 0; j < 4; ++j)
        O[(size_t)(row0 + j) * 1024 + col] = acc[i][nf][j];
    }
  }
}

// ==== mkred: MT[i] = bf16(sum_ks Part[ks][i]) ====
__global__ __launch_bounds__(256) void mkred_kernel(const float* __restrict__ Part,
                                                    short* __restrict__ MT) {
  const size_t i = ((size_t)blockIdx.x * 256 + threadIdx.x) * 4;
  f32x4 a = *(const f32x4*)(Part + i);
  f32x4 b = *(const f32x4*)(Part + 1048576 + i);
  f32x4 c = *(const f32x4*)(Part + 2097152 + i);
  f32x4 d = *(const f32x4*)(Part + 3145728 + i);
  s16x4 o;
#pragma unroll
  for (int j = 0; j < 4; ++j) o[j] = f2bf(a[j] + b[j] + c[j] + d[j]);
  *(s16x4*)(MT + i) = o;
}

// ==== qproj: A'[s][e] = sum_d X[s,d] MT[e,d]; tile 256x128, grid 256 (r15 verbatim) ====
__global__ __launch_bounds__(512, 2) void qproj_kernel(const short* __restrict__ Qc,
                                                       const short* __restrict__ MT,
                                                       short* __restrict__ Ap) {
  __shared__ short lds[36864];
  const int o = xswz(blockIdx.x, 256);
  const int bm = o >> 3, bn = o & 7;
  const int m0 = bm * 256, n0 = bn * 128;
  f32x4 acc[8][2];
#pragma unroll
  for (int i = 0; i < 8; ++i)
#pragma unroll
    for (int j = 0; j < 2; ++j) acc[i][j] = (f32x4){0.f, 0.f, 0.f, 0.f};
  gemm_core<1, 2, 3>(Qc, MT, 1024, 1024, m0, n0, 32, lds, acc);
  const int l = threadIdx.x & 63, w = threadIdx.x >> 6;
  const int wm = w >> 2, wn = w & 3, lr = l & 15, lg = l >> 4;
#pragma unroll
  for (int i = 0; i < 8; ++i) {
    const int row0 = m0 + wm * 128 + (i >> 2) * 64 + (i & 3) * 16 + lg * 4;
#pragma unroll
    for (int nf = 0; nf < 2; ++nf) {
      const int col = n0 + wn * 32 + nf * 16 + lr;
#pragma unroll
      for (int j = 0; j < 4; ++j)
        Ap[(size_t)(row0 + j) * 1024 + col] = f2bf(acc[i][nf][j]);
    }
  }
}

// ==== V projection -> VT[b][u][t]: tile 256x128, grid 256 (r15 verbatim) ====
__global__ __launch_bounds__(512, 2) void vproj_kernel(
    const short* __restrict__ Vc, const short* __restrict__ WTv,
    const float* __restrict__ bv, short* __restrict__ VT) {
  __shared__ short lds[36864];
  const int o = xswz(blockIdx.x, 256);
  const int bm = o >> 3, bn = o & 7;
  const int m0 = bm * 256, n0 = bn * 128;
  f32x4 acc[8][2];
#pragma unroll
  for (int i = 0; i < 8; ++i)
#pragma unroll
    for (int j = 0; j < 2; ++j) acc[i][j] = (f32x4){0.f, 0.f, 0.f, 0.f};
  gemm_core<1, 2, 3>(Vc, WTv, 1024, 1024, m0, n0, 32, lds, acc);
  const int tid = threadIdx.x;
  const int w = tid >> 6, l = tid & 63;
  const int wm = w >> 2, wn = w & 3, lr = l & 15, lg = l >> 4;
  __syncthreads();
  short* lt = lds;  // [u_local 0..127][t_local 0..255], stride 264
#pragma unroll
  for (int i = 0; i < 8; ++i) {
    const int tl = wm * 128 + (i >> 2) * 64 + (i & 3) * 16 + lg * 4;
#pragma unroll
    for (int nf = 0; nf < 2; ++nf) {
      const int ul = wn * 32 + nf * 16 + lr;
      const float bb = bv[n0 + ul];
      s16x4 pk;
#pragma unroll
      for (int j = 0; j < 4; ++j) pk[j] = f2bf(acc[i][nf][j] + bb);
      *(s16x4*)&lt[ul * 264 + tl] = pk;
    }
  }
  __syncthreads();
  const int b = m0 >> 11, t0 = m0 & 2047;
#pragma unroll
  for (int it = 0; it < 8; ++it) {
    const int cid = it * 512 + tid;
    const int u = cid >> 5, tc = cid & 31;
    s16x8 v8 = *(const s16x8*)&lt[u * 264 + tc * 8];
    *(s16x8*)(VT + ((size_t)b * 1024 + n0 + u) * 2048 + t0 + tc * 8) = v8;
  }
}

// ==== QK^T: scores=(A'.Vc^T + tvec)/32; tile 256x128, grid 512 (r15 verbatim) ====
__global__ __launch_bounds__(512, 4) void qkt_kernel(const short* __restrict__ Ap,
                                                     const short* __restrict__ Vc,
                                                     const float* __restrict__ tvec,
                                                     short* __restrict__ sb0,
                                                     short* __restrict__ sb3) {
  __shared__ short lds[36864];
  const int o = xswz(blockIdx.x, 512);
  const int bt = o >> 7, r = o & 127;
  const int bm = r >> 4, bn = r & 15;
  const short* A = Ap + (size_t)bt * 2097152;
  const short* B = Vc + (size_t)bt * 2097152;
  short* O = (bt < 3) ? (sb0 + (size_t)bt * 4194304) : sb3;
  const int m0 = bm * 256, n0 = bn * 128;
  f32x4 acc[8][2];
#pragma unroll
  for (int i = 0; i < 8; ++i)
#pragma unroll
    for (int j = 0; j < 2; ++j) acc[i][j] = (f32x4){0.f, 0.f, 0.f, 0.f};
  gemm_core<1, 2, 3>(A, B, 1024, 1024, m0, n0, 32, lds, acc);
  const int tid = threadIdx.x;
  const int w = tid >> 6, l = tid & 63;
  const int wm = w >> 2, wn = w & 3, lr = l & 15, lg = l >> 4;
  float tv[2];
#pragma unroll
  for (int nf = 0; nf < 2; ++nf) tv[nf] = tvec[bt * 2048 + n0 + wn * 32 + nf * 16 + lr];
#pragma unroll
  for (int i = 0; i < 8; ++i) {
    const int row0 = m0 + wm * 128 + (i >> 2) * 64 + (i & 3) * 16 + lg * 4;
#pragma unroll
    for (int nf = 0; nf < 2; ++nf) {
      const int col = n0 + wn * 32 + nf * 16 + lr;
#pragma unroll
      for (int j = 0; j < 4; ++j)
        O[(size_t)(row0 + j) * 2048 + col] = f2bf((acc[i][nf][j] + tv[nf]) * 0.03125f);
    }
  }
}

// ==== PV split-K=2: grid 512 (2 kh x 4 bt x 8 bm x 8 bn), nkt=32, 2 blk/CU ====
__global__ __launch_bounds__(512, 4) void pv_kernel(const short* __restrict__ sb0,
                                                    const short* __restrict__ sb3,
                                                    const short* __restrict__ VT,
                                                    float* __restrict__ Out,
                                                    float* __restrict__ Part) {
  __shared__ short lds[36864];
  const int o = xswz(blockIdx.x, 512);
  const int kh = o >> 8;                       // [0,2)
  const int bt = (o >> 6) & 3;                 // [0,4)
  const int bm = (o >> 3) & 7, bn = o & 7;     // bm:[0,8) bn:[0,8)
  const short* A = ((bt < 3) ? (sb0 + (size_t)bt * 4194304) : sb3) + kh * 1024;
  const short* B = VT + (size_t)bt * 2097152 + kh * 1024;
  float* O = (kh ? Part : Out) + (size_t)bt * 2097152;
  const int m0 = bm * 256, n0 = bn * 128;
  f32x4 acc[8][2];
#pragma unroll
  for (int i = 0; i < 8; ++i)
#pragma unroll
    for (int j = 0; j < 2; ++j) acc[i][j] = (f32x4){0.f, 0.f, 0.f, 0.f};
  gemm_core<1, 2, 3>(A, B, 2048, 2048, m0, n0, 32, lds, acc);
  const int l = threadIdx.x & 63, w = threadIdx.x >> 6;
  const int wm = w >> 2, wn = w & 3, lr = l & 15, lg = l >> 4;
#pragma unroll
  for (int i = 0; i < 8; ++i) {
    const int row0 = m0 + wm * 128 + (i >> 2) * 64 + (i & 3) * 16 + lg * 4;  // <= 2047
#pragma unroll
    for (int nf = 0; nf < 2; ++nf) {
      const int col = n0 + wn * 32 + nf * 16 + lr;  // <= 1023
#pragma unroll
      for (int j = 0; j < 4; ++j)
        O[(size_t)(row0 + j) * 1024 + col] = acc[i][nf][j];
    }
  }
}

// ============ add: d_out += Part (8M floats) ============
__global__ __launch_bounds__(256) void add_kernel(float* __restrict__ Out,
                                                  const float* __restrict__ Part) {
  const size_t i = ((size_t)blockIdx.x * 256 + threadIdx.x) * 4;
  f32x4 a = *(const f32x4*)(Out + i);
  f32x4 b = *(const f32x4*)(Part + i);
#pragma unroll
  for (int j = 0; j < 4; ++j) a[j] += b[j];
  *(f32x4*)(Out + i) = a;
}

// ============ Row softmax, in-place on bf16 scores ============
__global__ __launch_bounds__(256) void softmax_kernel(short* __restrict__ sb0,
                                                      short* __restrict__ sb3) {
  const int row = blockIdx.x;
  const int bt = row >> 11;
  short* p = ((bt < 3) ? (sb0 + (size_t)bt * 4194304) : sb3) + (size_t)(row & 2047) * 2048;
  const int tid = threadIdx.x;
  const int w = tid >> 6, l = tid & 63;
  s16x8 v = *(const s16x8*)(p + tid * 8);
  float f[8];
#pragma unroll
  for (int j = 0; j < 8; ++j) f[j] = bf2f(v[j]);
  float m = f[0];
#pragma unroll
  for (int j = 1; j < 8; ++j) m = fmaxf(m, f[j]);
#pragma unroll
  for (int o = 32; o > 0; o >>= 1) m = fmaxf(m, __shfl_xor(m, o, 64));
  __shared__ float redm[4], reds[4];
  if (l == 0) redm[w] = m;
  __syncthreads();
  m = fmaxf(fmaxf(redm[0], redm[1]), fmaxf(redm[2], redm[3]));
  float s = 0.f;
#pragma unroll
  for (int j = 0; j < 8; ++j) { f[j] = __expf(f[j] - m); s += f[j]; }
#pragma unroll
  for (int o = 32; o > 0; o >>= 1) s += __shfl_xor(s, o, 64);
  if (l == 0) reds[w] = s;
  __syncthreads();
  s = reds[0] + reds[1] + reds[2] + reds[3];
  const float inv = 1.f / s;
  s16x8 o8;
#pragma unroll
  for (int j = 0; j < 8; ++j) o8[j] = f2bf(f[j] * inv);
  *(s16x8*)(p + tid * 8) = o8;
}

// ============ launch ============
extern "C" void kernel_launch(void* const* d_in, const int* in_sizes, int n_in,
                              void* d_out, int out_size, void* d_ws, size_t ws_size,
                              hipStream_t stream) {
  const float* query = (const float*)d_in[0];
  const float* value = (const float*)d_in[1];
  const float* Wq = (const float*)d_in[2];
  const float* bq = (const float*)d_in[3];
  const float* Wk = (const float*)d_in[4];
  // bk: per-row-constant score contribution -> cancels in softmax
  const float* Wv = (const float*)d_in[6];
  const float* bv = (const float*)d_in[7];

  // Workspace (~80.2 MB of 86):
  //  0-2 Wqc | 2-4 Wkc | 4-6 MT | 6-8 WTv  [dead before qkt]
  //  8-24 Qc [prep->qproj]  24-40 Vc [prep->qkt]
  //  40-56 MPart fp32 [mker->mkred] THEN Ap [qproj->qkt]
  //  56-72 VT [vproj->pv]
  //  Sb: bt 0-2 @ 0-24 (dead-region reuse), bt 3 @ 72-80
  //  PvPart fp32 32MB @ 24-56 (Vc+Ap dead after qkt) [pv->add]
  //  80M: tvec(32KB) | +64K v1 | +128K flag
  char* ws = (char*)d_ws;
  short* Wqc = (short*)(ws);
  short* Wkc = (short*)(ws + ((size_t)2 << 20));
  short* MT  = (short*)(ws + ((size_t)4 << 20));
  short* WTv = (short*)(ws + ((size_t)6 << 20));
  short* Qc  = (short*)(ws + ((size_t)8 << 20));
  short* Vc  = (short*)(ws + ((size_t)24 << 20));
  float* MPart = (float*)(ws + ((size_t)40 << 20));
  short* Ap  = (short*)(ws + ((size_t)40 << 20));
  short* VT  = (short*)(ws + ((size_t)56 << 20));
  short* sb0 = (short*)(ws);
  short* sb3 = (short*)(ws + ((size_t)72 << 20));
  float* PvPart = (float*)(ws + ((size_t)24 << 20));
  float* tvec = (float*)(ws + ((size_t)80 << 20));
  float* v1   = (float*)(ws + ((size_t)80 << 20) + 65536);
  float* flagp = (float*)(ws + ((size_t)80 << 20) + 131072);

  prep_kernel<<<dim3(9472), 256, 0, stream>>>(query, value, Wq, Wk, Wv,
                                              Qc, Vc, Wqc, Wkc, WTv);
  bias0_kernel<<<dim3(1), 256, 0, stream>>>(Wk, bq, v1, flagp);
  tvec_kernel<<<dim3(32), 256, 0, stream>>>(value, v1, flagp, tvec);

  // MT = Wk.Wq^T via split-K=4 + reduce
  mker_kernel<<<dim3(128), 512, 0, stream>>>(Wkc, Wqc, MPart);
  mkred_kernel<<<dim3(1024), 256, 0, stream>>>(MPart, MT);

  // A' = X.MT^T (MPart dead -> Ap reuses its region); VT = (Y.Wv + bv)^T
  qproj_kernel<<<dim3(256), 512, 0, stream>>>(Qc, MT, Ap);
  vproj_kernel<<<dim3(256), 512, 0, stream>>>(Vc, WTv, bv, VT);

  // scores = (A'.Vc^T + tvec)/32
  qkt_kernel<<<dim3(512), 512, 0, stream>>>(Ap, Vc, tvec, sb0, sb3);
  softmax_kernel<<<dim3(8192), 256, 0, stream>>>(sb0, sb3);

  // out = P @ V, split-K=2 (Vc/Ap dead -> PvPart reuses 24-56M)
  pv_kernel<<<dim3(512), 512, 0, stream>>>(sb0, sb3, VT, (float*)d_out, PvPart);
  add_kernel<<<dim3(8192), 256, 0, stream>>>((float*)d_out, PvPart);
}

// Round 18
// 190.007 us; speedup vs baseline: 1.1149x; 1.0885x over previous
//
#include <hip/hip_runtime.h>
#include <hip/hip_bf16.h>
#include <stdint.h>

#define DEVINL __device__ __forceinline__

typedef __attribute__((ext_vector_type(4))) float f32x4;
typedef __attribute__((ext_vector_type(8))) __bf16 bfv8;
typedef __attribute__((ext_vector_type(8))) short s16x8;
typedef __attribute__((ext_vector_type(4))) short s16x4;

// ---- helpers ----
DEVINL short f2bf(float f) {  // fp32 -> bf16 bits, RTNE
  union { float f; unsigned u; } v; v.f = f;
  unsigned r = v.u + 0x7FFFu + ((v.u >> 16) & 1u);
  return (short)(r >> 16);
}
DEVINL float bf2f(short h) {
  union { unsigned u; float f; } v; v.u = ((unsigned)(unsigned short)h) << 16;
  return v.f;
}
DEVINL void gload_lds16(const void* g, void* l) {
  __builtin_amdgcn_global_load_lds((__attribute__((address_space(1))) unsigned*)(g),
                                   (__attribute__((address_space(3))) unsigned*)(l),
                                   16, 0, 0);
}
#define S_BARRIER() __builtin_amdgcn_s_barrier()
#define MEMORD() asm volatile("" ::: "memory")
template <int N> DEVINL void vmwaitc() {
  asm volatile("s_waitcnt vmcnt(%0)" :: "i"(N) : "memory");
}
// bijective XCD swizzle (n % 8 == 0)
DEVINL int xswz(int p, int n) { return (p & 7) * (n >> 3) + (p >> 3); }

// ======== r7 read-ahead core (best measured): 256x(NF*64) tile, BK=32, RING slots ========
template <int BU, int NF, int RING>
DEVINL void gemm_core(const short* __restrict__ Ag, const short* __restrict__ Bg,
                      int lda, int ldb, int m0, int n0, int nkt,
                      short* lds, f32x4 (&acc)[8][NF]) {
  constexpr int U = 2 + BU;
  constexpr int SLOT = 8192 + BU * 4096;
  const int tid = threadIdx.x;
  const int w = tid >> 6, l = tid & 63;
  const int wm = w >> 2, wn = w & 3;
  const int lr = l & 15, lg = l >> 4;
  const int stg_row = w * 16 + (l >> 2);
  const int stg_col = (((l & 3) ^ ((l >> 3) & 3)) << 3);
  const int ck = ((lg ^ ((lr >> 1) & 3)) << 3);
  const int aro = (wm * 128 + lr) * 32 + ck;
  const int bro = 8192 + (wn * (NF * 16) + lr) * 32 + ck;
  const int dW = w * 512;
#define STAGE_A(t) { short* S_ = lds + ((t) % RING) * SLOT;                                \
    gload_lds16(Ag + (size_t)(m0 + stg_row) * lda + (t) * 32 + stg_col, S_ + dW);          \
    gload_lds16(Ag + (size_t)(m0 + 128 + stg_row) * lda + (t) * 32 + stg_col,              \
                S_ + 4096 + dW); }
#define STAGE_B(t) { short* S_ = lds + ((t) % RING) * SLOT;                                \
    _Pragma("unroll")                                                                      \
    for (int u_ = 0; u_ < BU; ++u_)                                                        \
      gload_lds16(Bg + (size_t)(n0 + u_ * 128 + stg_row) * ldb + (t) * 32 + stg_col,       \
                  S_ + 8192 + u_ * 4096 + dW); }
#pragma unroll
  for (int t = 0; t < RING - 1; ++t) { STAGE_A(t); STAGE_B(t); }
  vmwaitc<(RING - 2) * U>(); S_BARRIER(); MEMORD();
  bfv8 aA[4], aB[4], bA[NF], bB[NF];
  {
    const short* Sp = lds;
#pragma unroll
    for (int mf = 0; mf < 4; ++mf) aA[mf] = *(const bfv8*)(Sp + aro + mf * 512);
#pragma unroll
    for (int nf = 0; nf < NF; ++nf) bA[nf] = *(const bfv8*)(Sp + bro + nf * 512);
  }
#pragma unroll 1
  for (int kt = 0; kt < nkt; kt += 2) {
    const short* S1 = lds + ((kt + 1) % RING) * SLOT;
    const short* S2 = lds + ((kt + 2) % RING) * SLOT;
    const short* S0 = lds + (kt % RING) * SLOT;
    if (kt + 2 < nkt) STAGE_A(kt + 2);
#pragma unroll
    for (int mf = 0; mf < 4; ++mf) aB[mf] = *(const bfv8*)(S0 + aro + 2048 + mf * 512);
#pragma unroll
    for (int mf = 0; mf < 4; ++mf)
#pragma unroll
      for (int nf = 0; nf < NF; ++nf)
        acc[mf][nf] = __builtin_amdgcn_mfma_f32_16x16x32_bf16(aA[mf], bA[nf], acc[mf][nf], 0, 0, 0);
    if (kt + 2 < nkt) vmwaitc<2>(); else vmwaitc<0>();
    S_BARRIER(); MEMORD();
    if (kt + 2 < nkt) STAGE_B(kt + 2);
#pragma unroll
    for (int mf = 0; mf < 4; ++mf) aA[mf] = *(const bfv8*)(S1 + aro + mf * 512);
#pragma unroll
    for (int nf = 0; nf < NF; ++nf) bB[nf] = *(const bfv8*)(S1 + bro + nf * 512);
#pragma unroll
    for (int mf = 0; mf < 4; ++mf)
#pragma unroll
      for (int nf = 0; nf < NF; ++nf)
        acc[4 + mf][nf] = __builtin_amdgcn_mfma_f32_16x16x32_bf16(aB[mf], bA[nf], acc[4 + mf][nf], 0, 0, 0);
    S_BARRIER(); MEMORD();
    if (kt + 3 < nkt) STAGE_A(kt + 3);
#pragma unroll
    for (int mf = 0; mf < 4; ++mf) aB[mf] = *(const bfv8*)(S1 + aro + 2048 + mf * 512);
#pragma unroll
    for (int mf = 0; mf < 4; ++mf)
#pragma unroll
      for (int nf = 0; nf < NF; ++nf)
        acc[mf][nf] = __builtin_amdgcn_mfma_f32_16x16x32_bf16(aA[mf], bB[nf], acc[mf][nf], 0, 0, 0);
    if (kt + 3 < nkt) vmwaitc<2>(); else vmwaitc<0>();
    S_BARRIER(); MEMORD();
    if (kt + 3 < nkt) STAGE_B(kt + 3);
    if (kt + 2 < nkt) {
#pragma unroll
      for (int mf = 0; mf < 4; ++mf) aA[mf] = *(const bfv8*)(S2 + aro + mf * 512);
#pragma unroll
      for (int nf = 0; nf < NF; ++nf) bA[nf] = *(const bfv8*)(S2 + bro + nf * 512);
    }
#pragma unroll
    for (int mf = 0; mf < 4; ++mf)
#pragma unroll
      for (int nf = 0; nf < NF; ++nf)
        acc[4 + mf][nf] = __builtin_amdgcn_mfma_f32_16x16x32_bf16(aB[mf], bB[nf], acc[4 + mf][nf], 0, 0, 0);
    S_BARRIER(); MEMORD();
  }
#undef STAGE_A
#undef STAGE_B
}

// ============ prep: cast X,Y,Wq,Wk -> bf16 + Wv transpose-cast ============
__global__ __launch_bounds__(256) void prep_kernel(
    const float* __restrict__ q, const float* __restrict__ v,
    const float* __restrict__ Wq, const float* __restrict__ Wk, const float* __restrict__ Wv,
    short* __restrict__ Qc, short* __restrict__ Vc,
    short* __restrict__ Wqc, short* __restrict__ Wkc, short* __restrict__ WTv) {
  __shared__ float tile[64][65];
  const int bx = blockIdx.x;
  if (bx < 9216) {
    const float* src; short* dst; int off;
    if (bx < 4096)      { src = q;  dst = Qc;  off = bx; }
    else if (bx < 8192) { src = v;  dst = Vc;  off = bx - 4096; }
    else if (bx < 8704) { src = Wq; dst = Wqc; off = bx - 8192; }
    else                { src = Wk; dst = Wkc; off = bx - 8704; }
    const size_t i = ((size_t)off * 256 + threadIdx.x) * 8;
    f32x4 x0 = *(const f32x4*)(src + i);
    f32x4 x1 = *(const f32x4*)(src + i + 4);
    s16x8 o;
#pragma unroll
    for (int j = 0; j < 4; ++j) { o[j] = f2bf(x0[j]); o[4 + j] = f2bf(x1[j]); }
    *(s16x8*)(dst + i) = o;
  } else {
    const int xx = bx - 9216;  // [0,256): Wv -> WTv[n][k]
    const int k0 = (xx & 15) << 6, n0 = (xx >> 4) << 6;
    const int c = threadIdx.x & 63, r0 = threadIdx.x >> 6;
#pragma unroll
    for (int i = 0; i < 16; ++i) {
      int r = (i << 2) + r0;
      tile[r][c] = Wv[(size_t)(k0 + r) * 1024 + n0 + c];
    }
    __syncthreads();
#pragma unroll
    for (int i = 0; i < 16; ++i) {
      int a = (i << 2) + r0;
      WTv[(size_t)(n0 + a) * 1024 + k0 + c] = f2bf(tile[c][a]);
    }
  }
}

// ============ bias correction: flag = any(bq != 0); v1 = Wk . bq ============
__global__ __launch_bounds__(256) void bias0_kernel(const float* __restrict__ Wk,
                                                    const float* __restrict__ bq,
                                                    float* __restrict__ v1,
                                                    float* __restrict__ flagp) {
  __shared__ float red[256];
  const int t = threadIdx.x;
  float any = 0.f;
  for (int i = t; i < 1024; i += 256) any += fabsf(bq[i]);
  red[t] = any; __syncthreads();
  for (int s = 128; s > 0; s >>= 1) { if (t < s) red[t] += red[t + s]; __syncthreads(); }
  const float fl = red[0];
  if (t == 0) *flagp = fl;
  if (fl != 0.f) {
    for (int r = t; r < 1024; r += 256) {
      float acc = 0.f;
      for (int u = 0; u < 1024; ++u) acc += Wk[(size_t)r * 1024 + u] * bq[u];
      v1[r] = acc;
    }
  }
}

// ============ tvec[t] = Y[t] . v1 (0 if flag==0) ============
__global__ __launch_bounds__(256) void tvec_kernel(const float* __restrict__ Y,
                                                   const float* __restrict__ v1,
                                                   const float* __restrict__ flagp,
                                                   float* __restrict__ tvec) {
  const int t = blockIdx.x * 256 + threadIdx.x;  // [0, 8192)
  if (*flagp == 0.f) { tvec[t] = 0.f; return; }
  float acc = 0.f;
  for (int d = 0; d < 1024; ++d) acc += Y[(size_t)t * 1024 + d] * v1[d];
  tvec[t] = acc;
}

// ==== mker split-K: Part[ks][e][d] = sum_{u in ks-quarter} Wk[e,u] Wq[d,u] ====
__global__ __launch_bounds__(512, 2) void mker_kernel(const short* __restrict__ Wkc,
                                                      const short* __restrict__ Wqc,
                                                      float* __restrict__ Part) {
  __shared__ short lds[36864];
  const int o = xswz(blockIdx.x, 128);
  const int ks = o >> 5, r = o & 31;
  const int bm = r >> 3, bn = r & 7;
  const int m0 = bm * 256, n0 = bn * 128;
  f32x4 acc[8][2];
#pragma unroll
  for (int i = 0; i < 8; ++i)
#pragma unroll
    for (int j = 0; j < 2; ++j) acc[i][j] = (f32x4){0.f, 0.f, 0.f, 0.f};
  gemm_core<1, 2, 3>(Wkc + ks * 256, Wqc + ks * 256, 1024, 1024, m0, n0, 8, lds, acc);
  float* O = Part + (size_t)ks * 1048576;
  const int l = threadIdx.x & 63, w = threadIdx.x >> 6;
  const int wm = w >> 2, wn = w & 3, lr = l & 15, lg = l >> 4;
#pragma unroll
  for (int i = 0; i < 8; ++i) {
    const int row0 = m0 + wm * 128 + (i >> 2) * 64 + (i & 3) * 16 + lg * 4;
#pragma unroll
    for (int nf = 0; nf < 2; ++nf) {
      const int col = n0 + wn * 32 + nf * 16 + lr;
#pragma unroll
      for (int j = 0; j < 4; ++j)
        O[(size_t)(row0 + j) * 1024 + col] = acc[i][nf][j];
    }
  }
}

// ==== mkred: MT[i] = bf16(sum_ks Part[ks][i]) ====
__global__ __launch_bounds__(256) void mkred_kernel(const float* __restrict__ Part,
                                                    short* __restrict__ MT) {
  const size_t i = ((size_t)blockIdx.x * 256 + threadIdx.x) * 4;
  f32x4 a = *(const f32x4*)(Part + i);
  f32x4 b = *(const f32x4*)(Part + 1048576 + i);
  f32x4 c = *(const f32x4*)(Part + 2097152 + i);
  f32x4 d = *(const f32x4*)(Part + 3145728 + i);
  s16x4 o;
#pragma unroll
  for (int j = 0; j < 4; ++j) o[j] = f2bf(a[j] + b[j] + c[j] + d[j]);
  *(s16x4*)(MT + i) = o;
}

// ==== qproj: A'[s][e] = sum_d X[s,d] MT[e,d]; tile 256x128, grid 256 ====
__global__ __launch_bounds__(512, 2) void qproj_kernel(const short* __restrict__ Qc,
                                                       const short* __restrict__ MT,
                                                       short* __restrict__ Ap) {
  __shared__ short lds[36864];
  const int o = xswz(blockIdx.x, 256);
  const int bm = o >> 3, bn = o & 7;
  const int m0 = bm * 256, n0 = bn * 128;
  f32x4 acc[8][2];
#pragma unroll
  for (int i = 0; i < 8; ++i)
#pragma unroll
    for (int j = 0; j < 2; ++j) acc[i][j] = (f32x4){0.f, 0.f, 0.f, 0.f};
  gemm_core<1, 2, 3>(Qc, MT, 1024, 1024, m0, n0, 32, lds, acc);
  const int l = threadIdx.x & 63, w = threadIdx.x >> 6;
  const int wm = w >> 2, wn = w & 3, lr = l & 15, lg = l >> 4;
#pragma unroll
  for (int i = 0; i < 8; ++i) {
    const int row0 = m0 + wm * 128 + (i >> 2) * 64 + (i & 3) * 16 + lg * 4;
#pragma unroll
    for (int nf = 0; nf < 2; ++nf) {
      const int col = n0 + wn * 32 + nf * 16 + lr;
#pragma unroll
      for (int j = 0; j < 4; ++j)
        Ap[(size_t)(row0 + j) * 1024 + col] = f2bf(acc[i][nf][j]);
    }
  }
}

// ==== V projection -> VT[b][u][t]: tile 256x128, grid 256 ====
__global__ __launch_bounds__(512, 2) void vproj_kernel(
    const short* __restrict__ Vc, const short* __restrict__ WTv,
    const float* __restrict__ bv, short* __restrict__ VT) {
  __shared__ short lds[36864];
  const int o = xswz(blockIdx.x, 256);
  const int bm = o >> 3, bn = o & 7;
  const int m0 = bm * 256, n0 = bn * 128;
  f32x4 acc[8][2];
#pragma unroll
  for (int i = 0; i < 8; ++i)
#pragma unroll
    for (int j = 0; j < 2; ++j) acc[i][j] = (f32x4){0.f, 0.f, 0.f, 0.f};
  gemm_core<1, 2, 3>(Vc, WTv, 1024, 1024, m0, n0, 32, lds, acc);
  const int tid = threadIdx.x;
  const int w = tid >> 6, l = tid & 63;
  const int wm = w >> 2, wn = w & 3, lr = l & 15, lg = l >> 4;
  __syncthreads();
  short* lt = lds;  // [u_local 0..127][t_local 0..255], stride 264
#pragma unroll
  for (int i = 0; i < 8; ++i) {
    const int tl = wm * 128 + (i >> 2) * 64 + (i & 3) * 16 + lg * 4;
#pragma unroll
    for (int nf = 0; nf < 2; ++nf) {
      const int ul = wn * 32 + nf * 16 + lr;
      const float bb = bv[n0 + ul];
      s16x4 pk;
#pragma unroll
      for (int j = 0; j < 4; ++j) pk[j] = f2bf(acc[i][nf][j] + bb);
      *(s16x4*)&lt[ul * 264 + tl] = pk;
    }
  }
  __syncthreads();
  const int b = m0 >> 11, t0 = m0 & 2047;
#pragma unroll
  for (int it = 0; it < 8; ++it) {
    const int cid = it * 512 + tid;
    const int u = cid >> 5, tc = cid & 31;
    s16x8 v8 = *(const s16x8*)&lt[u * 264 + tc * 8];
    *(s16x8*)(VT + ((size_t)b * 1024 + n0 + u) * 2048 + t0 + tc * 8) = v8;
  }
}

// ==== QK^T: scores=(A'.Vc^T + tvec)/32; tile 256x128, grid 512 ====
__global__ __launch_bounds__(512, 4) void qkt_kernel(const short* __restrict__ Ap,
                                                     const short* __restrict__ Vc,
                                                     const float* __restrict__ tvec,
                                                     short* __restrict__ sb0,
                                                     short* __restrict__ sb3) {
  __shared__ short lds[36864];
  const int o = xswz(blockIdx.x, 512);
  const int bt = o >> 7, r = o & 127;
  const int bm = r >> 4, bn = r & 15;
  const short* A = Ap + (size_t)bt * 2097152;
  const short* B = Vc + (size_t)bt * 2097152;
  short* O = (bt < 3) ? (sb0 + (size_t)bt * 4194304) : sb3;
  const int m0 = bm * 256, n0 = bn * 128;
  f32x4 acc[8][2];
#pragma unroll
  for (int i = 0; i < 8; ++i)
#pragma unroll
    for (int j = 0; j < 2; ++j) acc[i][j] = (f32x4){0.f, 0.f, 0.f, 0.f};
  gemm_core<1, 2, 3>(A, B, 1024, 1024, m0, n0, 32, lds, acc);
  const int tid = threadIdx.x;
  const int w = tid >> 6, l = tid & 63;
  const int wm = w >> 2, wn = w & 3, lr = l & 15, lg = l >> 4;
  float tv[2];
#pragma unroll
  for (int nf = 0; nf < 2; ++nf) tv[nf] = tvec[bt * 2048 + n0 + wn * 32 + nf * 16 + lr];
#pragma unroll
  for (int i = 0; i < 8; ++i) {
    const int row0 = m0 + wm * 128 + (i >> 2) * 64 + (i & 3) * 16 + lg * 4;
#pragma unroll
    for (int nf = 0; nf < 2; ++nf) {
      const int col = n0 + wn * 32 + nf * 16 + lr;
#pragma unroll
      for (int j = 0; j < 4; ++j)
        O[(size_t)(row0 + j) * 2048 + col] = f2bf((acc[i][nf][j] + tv[nf]) * 0.03125f);
    }
  }
}

// ==== PV: out = P @ V (VT layout); tile 256x128, grid 256 ====
__global__ __launch_bounds__(512, 2) void pv_kernel(const short* __restrict__ sb0,
                                                    const short* __restrict__ sb3,
                                                    const short* __restrict__ VT,
                                                    float* __restrict__ Out) {
  __shared__ short lds[36864];
  const int o = xswz(blockIdx.x, 256);
  const int bt = o >> 6, r = o & 63;
  const int bm = r >> 3, bn = r & 7;
  const short* A = (bt < 3) ? (sb0 + (size_t)bt * 4194304) : sb3;
  const short* B = VT + (size_t)bt * 2097152;
  float* O = Out + (size_t)bt * 2097152;
  const int m0 = bm * 256, n0 = bn * 128;
  f32x4 acc[8][2];
#pragma unroll
  for (int i = 0; i < 8; ++i)
#pragma unroll
    for (int j = 0; j < 2; ++j) acc[i][j] = (f32x4){0.f, 0.f, 0.f, 0.f};
  gemm_core<1, 2, 3>(A, B, 2048, 2048, m0, n0, 64, lds, acc);
  const int l = threadIdx.x & 63, w = threadIdx.x >> 6;
  const int wm = w >> 2, wn = w & 3, lr = l & 15, lg = l >> 4;
#pragma unroll
  for (int i = 0; i < 8; ++i) {
    const int row0 = m0 + wm * 128 + (i >> 2) * 64 + (i & 3) * 16 + lg * 4;
#pragma unroll
    for (int nf = 0; nf < 2; ++nf) {
      const int col = n0 + wn * 32 + nf * 16 + lr;
#pragma unroll
      for (int j = 0; j < 4; ++j)
        O[(size_t)(row0 + j) * 1024 + col] = acc[i][nf][j];
    }
  }
}

// ============ Row softmax, in-place on bf16 scores ============
__global__ __launch_bounds__(256) void softmax_kernel(short* __restrict__ sb0,
                                                      short* __restrict__ sb3) {
  const int row = blockIdx.x;
  const int bt = row >> 11;
  short* p = ((bt < 3) ? (sb0 + (size_t)bt * 4194304) : sb3) + (size_t)(row & 2047) * 2048;
  const int tid = threadIdx.x;
  const int w = tid >> 6, l = tid & 63;
  s16x8 v = *(const s16x8*)(p + tid * 8);
  float f[8];
#pragma unroll
  for (int j = 0; j < 8; ++j) f[j] = bf2f(v[j]);
  float m = f[0];
#pragma unroll
  for (int j = 1; j < 8; ++j) m = fmaxf(m, f[j]);
#pragma unroll
  for (int o = 32; o > 0; o >>= 1) m = fmaxf(m, __shfl_xor(m, o, 64));
  __shared__ float redm[4], reds[4];
  if (l == 0) redm[w] = m;
  __syncthreads();
  m = fmaxf(fmaxf(redm[0], redm[1]), fmaxf(redm[2], redm[3]));
  float s = 0.f;
#pragma unroll
  for (int j = 0; j < 8; ++j) { f[j] = __expf(f[j] - m); s += f[j]; }
#pragma unroll
  for (int o = 32; o > 0; o >>= 1) s += __shfl_xor(s, o, 64);
  if (l == 0) reds[w] = s;
  __syncthreads();
  s = reds[0] + reds[1] + reds[2] + reds[3];
  const float inv = 1.f / s;
  s16x8 o8;
#pragma unroll
  for (int j = 0; j < 8; ++j) o8[j] = f2bf(f[j] * inv);
  *(s16x8*)(p + tid * 8) = o8;
}

// ============ launch ============
extern "C" void kernel_launch(void* const* d_in, const int* in_sizes, int n_in,
                              void* d_out, int out_size, void* d_ws, size_t ws_size,
                              hipStream_t stream) {
  const float* query = (const float*)d_in[0];
  const float* value = (const float*)d_in[1];
  const float* Wq = (const float*)d_in[2];
  const float* bq = (const float*)d_in[3];
  const float* Wk = (const float*)d_in[4];
  // bk: per-row-constant score contribution -> cancels in softmax
  const float* Wv = (const float*)d_in[6];
  const float* bv = (const float*)d_in[7];

  // Workspace (~80.2 MB of 86):
  //  0-2 Wqc | 2-4 Wkc | 4-6 MT | 6-8 WTv  [dead before qkt]
  //  8-24 Qc [prep->qproj]  24-40 Vc [prep->qkt]
  //  40-56 MPart fp32 [mker->mkred] THEN Ap [qproj->qkt] (disjoint lifetimes)
  //  56-72 VT [vproj->pv]
  //  Sb: bt 0-2 @ 0-24 (dead-region reuse), bt 3 @ 72-80
  //  80M: tvec(32KB) | +64K v1 | +128K flag
  char* ws = (char*)d_ws;
  short* Wqc = (short*)(ws);
  short* Wkc = (short*)(ws + ((size_t)2 << 20));
  short* MT  = (short*)(ws + ((size_t)4 << 20));
  short* WTv = (short*)(ws + ((size_t)6 << 20));
  short* Qc  = (short*)(ws + ((size_t)8 << 20));
  short* Vc  = (short*)(ws + ((size_t)24 << 20));
  float* MPart = (float*)(ws + ((size_t)40 << 20));
  short* Ap  = (short*)(ws + ((size_t)40 << 20));
  short* VT  = (short*)(ws + ((size_t)56 << 20));
  short* sb0 = (short*)(ws);
  short* sb3 = (short*)(ws + ((size_t)72 << 20));
  float* tvec = (float*)(ws + ((size_t)80 << 20));
  float* v1   = (float*)(ws + ((size_t)80 << 20) + 65536);
  float* flagp = (float*)(ws + ((size_t)80 << 20) + 131072);

  prep_kernel<<<dim3(9472), 256, 0, stream>>>(query, value, Wq, Wk, Wv,
                                              Qc, Vc, Wqc, Wkc, WTv);
  bias0_kernel<<<dim3(1), 256, 0, stream>>>(Wk, bq, v1, flagp);
  tvec_kernel<<<dim3(32), 256, 0, stream>>>(value, v1, flagp, tvec);

  // MT = Wk.Wq^T via split-K=4 + reduce
  mker_kernel<<<dim3(128), 512, 0, stream>>>(Wkc, Wqc, MPart);
  mkred_kernel<<<dim3(1024), 256, 0, stream>>>(MPart, MT);

  // A' = X.MT^T (MPart dead -> Ap reuses its region)
  qproj_kernel<<<dim3(256), 512, 0, stream>>>(Qc, MT, Ap);
  vproj_kernel<<<dim3(256), 512, 0, stream>>>(Vc, WTv, bv, VT);

  // scores = (A'.Vc^T + tvec)/32
  qkt_kernel<<<dim3(512), 512, 0, stream>>>(Ap, Vc, tvec, sb0, sb3);
  softmax_kernel<<<dim3(8192), 256, 0, stream>>>(sb0, sb3);
  // out = P @ V
  pv_kernel<<<dim3(256), 512, 0, stream>>>(sb0, sb3, VT, (float*)d_out);
}

// Round 19
// 185.582 us; speedup vs baseline: 1.1415x; 1.0238x over previous
//
#include <hip/hip_runtime.h>
#include <hip/hip_bf16.h>
#include <stdint.h>

#define DEVINL __device__ __forceinline__

typedef __attribute__((ext_vector_type(4))) float f32x4;
typedef __attribute__((ext_vector_type(8))) __bf16 bfv8;
typedef __attribute__((ext_vector_type(8))) short s16x8;
typedef __attribute__((ext_vector_type(4))) short s16x4;

// ---- helpers ----
DEVINL short f2bf(float f) {  // fp32 -> bf16 bits, RTNE
  union { float f; unsigned u; } v; v.f = f;
  unsigned r = v.u + 0x7FFFu + ((v.u >> 16) & 1u);
  return (short)(r >> 16);
}
DEVINL float bf2f(short h) {
  union { unsigned u; float f; } v; v.u = ((unsigned)(unsigned short)h) << 16;
  return v.f;
}
DEVINL void gload_lds16(const void* g, void* l) {
  __builtin_amdgcn_global_load_lds((__attribute__((address_space(1))) unsigned*)(g),
                                   (__attribute__((address_space(3))) unsigned*)(l),
                                   16, 0, 0);
}
#define S_BARRIER() __builtin_amdgcn_s_barrier()
#define MEMORD() asm volatile("" ::: "memory")
template <int N> DEVINL void vmwaitc() {
  asm volatile("s_waitcnt vmcnt(%0)" :: "i"(N) : "memory");
}
// bijective XCD swizzle (n % 8 == 0)
DEVINL int xswz(int p, int n) { return (p & 7) * (n >> 3) + (p >> 3); }

// ======== r7 read-ahead core (best measured): 256x(NF*64) tile, BK=32, RING slots ========
template <int BU, int NF, int RING>
DEVINL void gemm_core(const short* __restrict__ Ag, const short* __restrict__ Bg,
                      int lda, int ldb, int m0, int n0, int nkt,
                      short* lds, f32x4 (&acc)[8][NF]) {
  constexpr int U = 2 + BU;
  constexpr int SLOT = 8192 + BU * 4096;
  const int tid = threadIdx.x;
  const int w = tid >> 6, l = tid & 63;
  const int wm = w >> 2, wn = w & 3;
  const int lr = l & 15, lg = l >> 4;
  const int stg_row = w * 16 + (l >> 2);
  const int stg_col = (((l & 3) ^ ((l >> 3) & 3)) << 3);
  const int ck = ((lg ^ ((lr >> 1) & 3)) << 3);
  const int aro = (wm * 128 + lr) * 32 + ck;
  const int bro = 8192 + (wn * (NF * 16) + lr) * 32 + ck;
  const int dW = w * 512;
#define STAGE_A(t) { short* S_ = lds + ((t) % RING) * SLOT;                                \
    gload_lds16(Ag + (size_t)(m0 + stg_row) * lda + (t) * 32 + stg_col, S_ + dW);          \
    gload_lds16(Ag + (size_t)(m0 + 128 + stg_row) * lda + (t) * 32 + stg_col,              \
                S_ + 4096 + dW); }
#define STAGE_B(t) { short* S_ = lds + ((t) % RING) * SLOT;                                \
    _Pragma("unroll")                                                                      \
    for (int u_ = 0; u_ < BU; ++u_)                                                        \
      gload_lds16(Bg + (size_t)(n0 + u_ * 128 + stg_row) * ldb + (t) * 32 + stg_col,       \
                  S_ + 8192 + u_ * 4096 + dW); }
#pragma unroll
  for (int t = 0; t < RING - 1; ++t) { STAGE_A(t); STAGE_B(t); }
  vmwaitc<(RING - 2) * U>(); S_BARRIER(); MEMORD();
  bfv8 aA[4], aB[4], bA[NF], bB[NF];
  {
    const short* Sp = lds;
#pragma unroll
    for (int mf = 0; mf < 4; ++mf) aA[mf] = *(const bfv8*)(Sp + aro + mf * 512);
#pragma unroll
    for (int nf = 0; nf < NF; ++nf) bA[nf] = *(const bfv8*)(Sp + bro + nf * 512);
  }
#pragma unroll 1
  for (int kt = 0; kt < nkt; kt += 2) {
    const short* S1 = lds + ((kt + 1) % RING) * SLOT;
    const short* S2 = lds + ((kt + 2) % RING) * SLOT;
    const short* S0 = lds + (kt % RING) * SLOT;
    if (kt + 2 < nkt) STAGE_A(kt + 2);
#pragma unroll
    for (int mf = 0; mf < 4; ++mf) aB[mf] = *(const bfv8*)(S0 + aro + 2048 + mf * 512);
#pragma unroll
    for (int mf = 0; mf < 4; ++mf)
#pragma unroll
      for (int nf = 0; nf < NF; ++nf)
        acc[mf][nf] = __builtin_amdgcn_mfma_f32_16x16x32_bf16(aA[mf], bA[nf], acc[mf][nf], 0, 0, 0);
    if (kt + 2 < nkt) vmwaitc<2>(); else vmwaitc<0>();
    S_BARRIER(); MEMORD();
    if (kt + 2 < nkt) STAGE_B(kt + 2);
#pragma unroll
    for (int mf = 0; mf < 4; ++mf) aA[mf] = *(const bfv8*)(S1 + aro + mf * 512);
#pragma unroll
    for (int nf = 0; nf < NF; ++nf) bB[nf] = *(const bfv8*)(S1 + bro + nf * 512);
#pragma unroll
    for (int mf = 0; mf < 4; ++mf)
#pragma unroll
      for (int nf = 0; nf < NF; ++nf)
        acc[4 + mf][nf] = __builtin_amdgcn_mfma_f32_16x16x32_bf16(aB[mf], bA[nf], acc[4 + mf][nf], 0, 0, 0);
    S_BARRIER(); MEMORD();
    if (kt + 3 < nkt) STAGE_A(kt + 3);
#pragma unroll
    for (int mf = 0; mf < 4; ++mf) aB[mf] = *(const bfv8*)(S1 + aro + 2048 + mf * 512);
#pragma unroll
    for (int mf = 0; mf < 4; ++mf)
#pragma unroll
      for (int nf = 0; nf < NF; ++nf)
        acc[mf][nf] = __builtin_amdgcn_mfma_f32_16x16x32_bf16(aA[mf], bB[nf], acc[mf][nf], 0, 0, 0);
    if (kt + 3 < nkt) vmwaitc<2>(); else vmwaitc<0>();
    S_BARRIER(); MEMORD();
    if (kt + 3 < nkt) STAGE_B(kt + 3);
    if (kt + 2 < nkt) {
#pragma unroll
      for (int mf = 0; mf < 4; ++mf) aA[mf] = *(const bfv8*)(S2 + aro + mf * 512);
#pragma unroll
      for (int nf = 0; nf < NF; ++nf) bA[nf] = *(const bfv8*)(S2 + bro + nf * 512);
    }
#pragma unroll
    for (int mf = 0; mf < 4; ++mf)
#pragma unroll
      for (int nf = 0; nf < NF; ++nf)
        acc[4 + mf][nf] = __builtin_amdgcn_mfma_f32_16x16x32_bf16(aB[mf], bB[nf], acc[4 + mf][nf], 0, 0, 0);
    S_BARRIER(); MEMORD();
  }
#undef STAGE_A
#undef STAGE_B
}

// ==== prep: cast X,Y,Wq,Wk -> bf16 + Wv transpose-cast + (bx==9472) bias0 block ====
__global__ __launch_bounds__(256) void prep_kernel(
    const float* __restrict__ q, const float* __restrict__ v,
    const float* __restrict__ Wq, const float* __restrict__ Wk, const float* __restrict__ Wv,
    const float* __restrict__ bq,
    short* __restrict__ Qc, short* __restrict__ Vc,
    short* __restrict__ Wqc, short* __restrict__ Wkc, short* __restrict__ WTv,
    float* __restrict__ v1, float* __restrict__ flagp) {
  __shared__ float tile[64][65];
  const int bx = blockIdx.x;
  if (bx < 9216) {
    const float* src; short* dst; int off;
    if (bx < 4096)      { src = q;  dst = Qc;  off = bx; }
    else if (bx < 8192) { src = v;  dst = Vc;  off = bx - 4096; }
    else if (bx < 8704) { src = Wq; dst = Wqc; off = bx - 8192; }
    else                { src = Wk; dst = Wkc; off = bx - 8704; }
    const size_t i = ((size_t)off * 256 + threadIdx.x) * 8;
    f32x4 x0 = *(const f32x4*)(src + i);
    f32x4 x1 = *(const f32x4*)(src + i + 4);
    s16x8 o;
#pragma unroll
    for (int j = 0; j < 4; ++j) { o[j] = f2bf(x0[j]); o[4 + j] = f2bf(x1[j]); }
    *(s16x8*)(dst + i) = o;
  } else if (bx < 9472) {
    const int xx = bx - 9216;  // [0,256): Wv -> WTv[n][k]
    const int k0 = (xx & 15) << 6, n0 = (xx >> 4) << 6;
    const int c = threadIdx.x & 63, r0 = threadIdx.x >> 6;
#pragma unroll
    for (int i = 0; i < 16; ++i) {
      int r = (i << 2) + r0;
      tile[r][c] = Wv[(size_t)(k0 + r) * 1024 + n0 + c];
    }
    __syncthreads();
#pragma unroll
    for (int i = 0; i < 16; ++i) {
      int a = (i << 2) + r0;
      WTv[(size_t)(n0 + a) * 1024 + k0 + c] = f2bf(tile[c][a]);
    }
  } else {
    // ---- bias0 block: flag = sum|bq|; if nonzero, v1 = Wk . bq ----
    float* red = &tile[0][0];
    const int t = threadIdx.x;
    float any = 0.f;
    for (int i = t; i < 1024; i += 256) any += fabsf(bq[i]);
    red[t] = any; __syncthreads();
    for (int s = 128; s > 0; s >>= 1) { if (t < s) red[t] += red[t + s]; __syncthreads(); }
    const float fl = red[0];
    if (t == 0) *flagp = fl;
    if (fl != 0.f) {
      for (int r = t; r < 1024; r += 256) {
        float acc = 0.f;
        for (int u = 0; u < 1024; ++u) acc += Wk[(size_t)r * 1024 + u] * bq[u];
        v1[r] = acc;
      }
    }
  }
}

// ==== mker split-K: Part[ks][e][d] = sum_{u in ks-quarter} Wk[e,u] Wq[d,u] ====
__global__ __launch_bounds__(512, 2) void mker_kernel(const short* __restrict__ Wkc,
                                                      const short* __restrict__ Wqc,
                                                      float* __restrict__ Part) {
  __shared__ short lds[36864];
  const int o = xswz(blockIdx.x, 128);
  const int ks = o >> 5, r = o & 31;
  const int bm = r >> 3, bn = r & 7;
  const int m0 = bm * 256, n0 = bn * 128;
  f32x4 acc[8][2];
#pragma unroll
  for (int i = 0; i < 8; ++i)
#pragma unroll
    for (int j = 0; j < 2; ++j) acc[i][j] = (f32x4){0.f, 0.f, 0.f, 0.f};
  gemm_core<1, 2, 3>(Wkc + ks * 256, Wqc + ks * 256, 1024, 1024, m0, n0, 8, lds, acc);
  float* O = Part + (size_t)ks * 1048576;
  const int l = threadIdx.x & 63, w = threadIdx.x >> 6;
  const int wm = w >> 2, wn = w & 3, lr = l & 15, lg = l >> 4;
#pragma unroll
  for (int i = 0; i < 8; ++i) {
    const int row0 = m0 + wm * 128 + (i >> 2) * 64 + (i & 3) * 16 + lg * 4;
#pragma unroll
    for (int nf = 0; nf < 2; ++nf) {
      const int col = n0 + wn * 32 + nf * 16 + lr;
#pragma unroll
      for (int j = 0; j < 4; ++j)
        O[(size_t)(row0 + j) * 1024 + col] = acc[i][nf][j];
    }
  }
}

// ==== mkred (blocks 0-1023): MT = bf16(sum Part); tvec (blocks 1024-1055) fused ====
__global__ __launch_bounds__(256) void mkred_kernel(const float* __restrict__ Part,
                                                    short* __restrict__ MT,
                                                    const float* __restrict__ Y,
                                                    const float* __restrict__ v1,
                                                    const float* __restrict__ flagp,
                                                    float* __restrict__ tvec) {
  const int bx = blockIdx.x;
  if (bx < 1024) {
    const size_t i = ((size_t)bx * 256 + threadIdx.x) * 4;
    f32x4 a = *(const f32x4*)(Part + i);
    f32x4 b = *(const f32x4*)(Part + 1048576 + i);
    f32x4 c = *(const f32x4*)(Part + 2097152 + i);
    f32x4 d = *(const f32x4*)(Part + 3145728 + i);
    s16x4 o;
#pragma unroll
    for (int j = 0; j < 4; ++j) o[j] = f2bf(a[j] + b[j] + c[j] + d[j]);
    *(s16x4*)(MT + i) = o;
  } else {
    const int t = (bx - 1024) * 256 + threadIdx.x;  // [0, 8192)
    if (*flagp == 0.f) { tvec[t] = 0.f; return; }
    float acc = 0.f;
    for (int d = 0; d < 1024; ++d) acc += Y[(size_t)t * 1024 + d] * v1[d];
    tvec[t] = acc;
  }
}

// ==== qproj: A'[s][e] = sum_d X[s,d] MT[e,d]; tile 256x128, grid 256 ====
__global__ __launch_bounds__(512, 2) void qproj_kernel(const short* __restrict__ Qc,
                                                       const short* __restrict__ MT,
                                                       short* __restrict__ Ap) {
  __shared__ short lds[36864];
  const int o = xswz(blockIdx.x, 256);
  const int bm = o >> 3, bn = o & 7;
  const int m0 = bm * 256, n0 = bn * 128;
  f32x4 acc[8][2];
#pragma unroll
  for (int i = 0; i < 8; ++i)
#pragma unroll
    for (int j = 0; j < 2; ++j) acc[i][j] = (f32x4){0.f, 0.f, 0.f, 0.f};
  gemm_core<1, 2, 3>(Qc, MT, 1024, 1024, m0, n0, 32, lds, acc);
  const int l = threadIdx.x & 63, w = threadIdx.x >> 6;
  const int wm = w >> 2, wn = w & 3, lr = l & 15, lg = l >> 4;
#pragma unroll
  for (int i = 0; i < 8; ++i) {
    const int row0 = m0 + wm * 128 + (i >> 2) * 64 + (i & 3) * 16 + lg * 4;
#pragma unroll
    for (int nf = 0; nf < 2; ++nf) {
      const int col = n0 + wn * 32 + nf * 16 + lr;
#pragma unroll
      for (int j = 0; j < 4; ++j)
        Ap[(size_t)(row0 + j) * 1024 + col] = f2bf(acc[i][nf][j]);
    }
  }
}

// ==== V projection -> VT[b][u][t]: tile 256x128, grid 256 ====
__global__ __launch_bounds__(512, 2) void vproj_kernel(
    const short* __restrict__ Vc, const short* __restrict__ WTv,
    const float* __restrict__ bv, short* __restrict__ VT) {
  __shared__ short lds[36864];
  const int o = xswz(blockIdx.x, 256);
  const int bm = o >> 3, bn = o & 7;
  const int m0 = bm * 256, n0 = bn * 128;
  f32x4 acc[8][2];
#pragma unroll
  for (int i = 0; i < 8; ++i)
#pragma unroll
    for (int j = 0; j < 2; ++j) acc[i][j] = (f32x4){0.f, 0.f, 0.f, 0.f};
  gemm_core<1, 2, 3>(Vc, WTv, 1024, 1024, m0, n0, 32, lds, acc);
  const int tid = threadIdx.x;
  const int w = tid >> 6, l = tid & 63;
  const int wm = w >> 2, wn = w & 3, lr = l & 15, lg = l >> 4;
  __syncthreads();
  short* lt = lds;  // [u_local 0..127][t_local 0..255], stride 264
#pragma unroll
  for (int i = 0; i < 8; ++i) {
    const int tl = wm * 128 + (i >> 2) * 64 + (i & 3) * 16 + lg * 4;
#pragma unroll
    for (int nf = 0; nf < 2; ++nf) {
      const int ul = wn * 32 + nf * 16 + lr;
      const float bb = bv[n0 + ul];
      s16x4 pk;
#pragma unroll
      for (int j = 0; j < 4; ++j) pk[j] = f2bf(acc[i][nf][j] + bb);
      *(s16x4*)&lt[ul * 264 + tl] = pk;
    }
  }
  __syncthreads();
  const int b = m0 >> 11, t0 = m0 & 2047;
#pragma unroll
  for (int it = 0; it < 8; ++it) {
    const int cid = it * 512 + tid;
    const int u = cid >> 5, tc = cid & 31;
    s16x8 v8 = *(const s16x8*)&lt[u * 264 + tc * 8];
    *(s16x8*)(VT + ((size_t)b * 1024 + n0 + u) * 2048 + t0 + tc * 8) = v8;
  }
}

// ==== QK^T: scores=(A'.Vc^T + tvec)/32; tile 256x128, grid 512 ====
__global__ __launch_bounds__(512, 4) void qkt_kernel(const short* __restrict__ Ap,
                                                     const short* __restrict__ Vc,
                                                     const float* __restrict__ tvec,
                                                     short* __restrict__ sb0,
                                                     short* __restrict__ sb3) {
  __shared__ short lds[36864];
  const int o = xswz(blockIdx.x, 512);
  const int bt = o >> 7, r = o & 127;
  const int bm = r >> 4, bn = r & 15;
  const short* A = Ap + (size_t)bt * 2097152;
  const short* B = Vc + (size_t)bt * 2097152;
  short* O = (bt < 3) ? (sb0 + (size_t)bt * 4194304) : sb3;
  const int m0 = bm * 256, n0 = bn * 128;
  f32x4 acc[8][2];
#pragma unroll
  for (int i = 0; i < 8; ++i)
#pragma unroll
    for (int j = 0; j < 2; ++j) acc[i][j] = (f32x4){0.f, 0.f, 0.f, 0.f};
  gemm_core<1, 2, 3>(A, B, 1024, 1024, m0, n0, 32, lds, acc);
  const int tid = threadIdx.x;
  const int w = tid >> 6, l = tid & 63;
  const int wm = w >> 2, wn = w & 3, lr = l & 15, lg = l >> 4;
  float tv[2];
#pragma unroll
  for (int nf = 0; nf < 2; ++nf) tv[nf] = tvec[bt * 2048 + n0 + wn * 32 + nf * 16 + lr];
#pragma unroll
  for (int i = 0; i < 8; ++i) {
    const int row0 = m0 + wm * 128 + (i >> 2) * 64 + (i & 3) * 16 + lg * 4;
#pragma unroll
    for (int nf = 0; nf < 2; ++nf) {
      const int col = n0 + wn * 32 + nf * 16 + lr;
#pragma unroll
      for (int j = 0; j < 4; ++j)
        O[(size_t)(row0 + j) * 2048 + col] = f2bf((acc[i][nf][j] + tv[nf]) * 0.03125f);
    }
  }
}

// ==== PV: out = P @ V (VT layout); tile 256x128, grid 256 ====
__global__ __launch_bounds__(512, 2) void pv_kernel(const short* __restrict__ sb0,
                                                    const short* __restrict__ sb3,
                                                    const short* __restrict__ VT,
                                                    float* __restrict__ Out) {
  __shared__ short lds[36864];
  const int o = xswz(blockIdx.x, 256);
  const int bt = o >> 6, r = o & 63;
  const int bm = r >> 3, bn = r & 7;
  const short* A = (bt < 3) ? (sb0 + (size_t)bt * 4194304) : sb3;
  const short* B = VT + (size_t)bt * 2097152;
  float* O = Out + (size_t)bt * 2097152;
  const int m0 = bm * 256, n0 = bn * 128;
  f32x4 acc[8][2];
#pragma unroll
  for (int i = 0; i < 8; ++i)
#pragma unroll
    for (int j = 0; j < 2; ++j) acc[i][j] = (f32x4){0.f, 0.f, 0.f, 0.f};
  gemm_core<1, 2, 3>(A, B, 2048, 2048, m0, n0, 64, lds, acc);
  const int l = threadIdx.x & 63, w = threadIdx.x >> 6;
  const int wm = w >> 2, wn = w & 3, lr = l & 15, lg = l >> 4;
#pragma unroll
  for (int i = 0; i < 8; ++i) {
    const int row0 = m0 + wm * 128 + (i >> 2) * 64 + (i & 3) * 16 + lg * 4;
#pragma unroll
    for (int nf = 0; nf < 2; ++nf) {
      const int col = n0 + wn * 32 + nf * 16 + lr;
#pragma unroll
      for (int j = 0; j < 4; ++j)
        O[(size_t)(row0 + j) * 1024 + col] = acc[i][nf][j];
    }
  }
}

// ============ Row softmax, in-place on bf16 scores ============
__global__ __launch_bounds__(256) void softmax_kernel(short* __restrict__ sb0,
                                                      short* __restrict__ sb3) {
  const int row = blockIdx.x;
  const int bt = row >> 11;
  short* p = ((bt < 3) ? (sb0 + (size_t)bt * 4194304) : sb3) + (size_t)(row & 2047) * 2048;
  const int tid = threadIdx.x;
  const int w = tid >> 6, l = tid & 63;
  s16x8 v = *(const s16x8*)(p + tid * 8);
  float f[8];
#pragma unroll
  for (int j = 0; j < 8; ++j) f[j] = bf2f(v[j]);
  float m = f[0];
#pragma unroll
  for (int j = 1; j < 8; ++j) m = fmaxf(m, f[j]);
#pragma unroll
  for (int o = 32; o > 0; o >>= 1) m = fmaxf(m, __shfl_xor(m, o, 64));
  __shared__ float redm[4], reds[4];
  if (l == 0) redm[w] = m;
  __syncthreads();
  m = fmaxf(fmaxf(redm[0], redm[1]), fmaxf(redm[2], redm[3]));
  float s = 0.f;
#pragma unroll
  for (int j = 0; j < 8; ++j) { f[j] = __expf(f[j] - m); s += f[j]; }
#pragma unroll
  for (int o = 32; o > 0; o >>= 1) s += __shfl_xor(s, o, 64);
  if (l == 0) reds[w] = s;
  __syncthreads();
  s = reds[0] + reds[1] + reds[2] + reds[3];
  const float inv = 1.f / s;
  s16x8 o8;
#pragma unroll
  for (int j = 0; j < 8; ++j) o8[j] = f2bf(f[j] * inv);
  *(s16x8*)(p + tid * 8) = o8;
}

// ============ launch ============
extern "C" void kernel_launch(void* const* d_in, const int* in_sizes, int n_in,
                              void* d_out, int out_size, void* d_ws, size_t ws_size,
                              hipStream_t stream) {
  const float* query = (const float*)d_in[0];
  const float* value = (const float*)d_in[1];
  const float* Wq = (const float*)d_in[2];
  const float* bq = (const float*)d_in[3];
  const float* Wk = (const float*)d_in[4];
  // bk: per-row-constant score contribution -> cancels in softmax
  const float* Wv = (const float*)d_in[6];
  const float* bv = (const float*)d_in[7];

  // Workspace (~80.2 MB of 86):
  //  0-2 Wqc | 2-4 Wkc | 4-6 MT | 6-8 WTv  [dead before qkt]
  //  8-24 Qc [prep->qproj]  24-40 Vc [prep->qkt]
  //  40-56 MPart fp32 [mker->mkred] THEN Ap [qproj->qkt] (disjoint lifetimes)
  //  56-72 VT [vproj->pv]
  //  Sb: bt 0-2 @ 0-24 (dead-region reuse), bt 3 @ 72-80
  //  80M: tvec(32KB) | +64K v1 | +128K flag
  char* ws = (char*)d_ws;
  short* Wqc = (short*)(ws);
  short* Wkc = (short*)(ws + ((size_t)2 << 20));
  short* MT  = (short*)(ws + ((size_t)4 << 20));
  short* WTv = (short*)(ws + ((size_t)6 << 20));
  short* Qc  = (short*)(ws + ((size_t)8 << 20));
  short* Vc  = (short*)(ws + ((size_t)24 << 20));
  float* MPart = (float*)(ws + ((size_t)40 << 20));
  short* Ap  = (short*)(ws + ((size_t)40 << 20));
  short* VT  = (short*)(ws + ((size_t)56 << 20));
  short* sb0 = (short*)(ws);
  short* sb3 = (short*)(ws + ((size_t)72 << 20));
  float* tvec = (float*)(ws + ((size_t)80 << 20));
  float* v1   = (float*)(ws + ((size_t)80 << 20) + 65536);
  float* flagp = (float*)(ws + ((size_t)80 << 20) + 131072);

  // prep (+ fused bias0 block)
  prep_kernel<<<dim3(9473), 256, 0, stream>>>(query, value, Wq, Wk, Wv, bq,
                                              Qc, Vc, Wqc, Wkc, WTv, v1, flagp);

  // MT = Wk.Wq^T via split-K=4; reduce (+ fused tvec blocks)
  mker_kernel<<<dim3(128), 512, 0, stream>>>(Wkc, Wqc, MPart);
  mkred_kernel<<<dim3(1056), 256, 0, stream>>>(MPart, MT, value, v1, flagp, tvec);

  // A' = X.MT^T (MPart dead -> Ap reuses its region)
  qproj_kernel<<<dim3(256), 512, 0, stream>>>(Qc, MT, Ap);
  vproj_kernel<<<dim3(256), 512, 0, stream>>>(Vc, WTv, bv, VT);

  // scores = (A'.Vc^T + tvec)/32
  qkt_kernel<<<dim3(512), 512, 0, stream>>>(Ap, Vc, tvec, sb0, sb3);
  softmax_kernel<<<dim3(8192), 256, 0, stream>>>(sb0, sb3);
  // out = P @ V
  pv_kernel<<<dim3(256), 512, 0, stream>>>(sb0, sb3, VT, (float*)d_out);
}